// Round 5
// baseline (8472.183 us; speedup 1.0000x reference)
//
#include <hip/hip_runtime.h>
#include <hip/hip_bf16.h>

// Shapes
#define BB   64
#define NN   512
#define EE   2048
#define FINK 300
#define DD   256
#define AAK  64
#define NHH  4
#define DHH  64
#define BN_TOT (BB*NN)    // 32768
#define BE_TOT (BB*EE)    // 131072
#define EPSF 1e-5f

using bf16 = __hip_bfloat16;

__device__ __forceinline__ float tf(float x) { return x; }
__device__ __forceinline__ float tf(bf16 x)  { return __bfloat162float(x); }
__device__ __forceinline__ void  stv(float* p, float v) { *p = v; }
__device__ __forceinline__ void  stv(bf16*  p, float v) { *p = __float2bfloat16(v); }

// Int dtype probe: lengths[1] read as int32 is in [256,512] iff storage is
// int32; it is the zero hi-word of lengths[0] iff storage is int64 (LE).
__global__ void detect_kernel(const int* __restrict__ lengths, int* __restrict__ flags)
{
    flags[1] = (lengths[1] == 0) ? 1 : 0;
}

// Canonicalize int input -> int32 (int64 values are small nonneg; low word, LE)
__global__ void conv_i(const void* __restrict__ src, int* __restrict__ dst, int n,
                       const int* __restrict__ flags)
{
    int i = blockIdx.x * 256 + threadIdx.x;
    if (i >= n) return;
    const int* s = (const int*)src;
    dst[i] = s[flags[1] ? (i << 1) : i];
}

// ---------------------------------------------------------------------------
// Generic tiled GEMM: C[m,n] = sum_k A[m,k] * W[n*ldw+k]  (+bias, +relu)
// A: f32 or bf16; W,bias: f32; C: f32 or bf16.
// ---------------------------------------------------------------------------
template<typename TA, typename TC>
__global__ void gemm_kernel(const TA* __restrict__ A, const float* __restrict__ W,
                            const float* __restrict__ bias, TC* __restrict__ C,
                            int M, int N, int K, int ldw, int relu)
{
    __shared__ float As[16][17];
    __shared__ float Ws[16][17];
    int tx = threadIdx.x, ty = threadIdx.y;
    int m  = blockIdx.y * 16 + ty;
    int n  = blockIdx.x * 16 + tx;
    float acc = 0.f;
    for (int k0 = 0; k0 < K; k0 += 16) {
        int ka = k0 + tx;
        As[ty][tx] = (m < M && ka < K) ? tf(A[(size_t)m * K + ka]) : 0.f;
        int nw = blockIdx.x * 16 + ty;
        Ws[ty][tx] = (nw < N && ka < K) ? W[(size_t)nw * ldw + ka] : 0.f;
        __syncthreads();
#pragma unroll
        for (int kk = 0; kk < 16; kk++) acc += As[ty][kk] * Ws[tx][kk];
        __syncthreads();
    }
    if (m < M && n < N) {
        if (bias) acc += bias[n];
        if (relu) acc = fmaxf(acc, 0.f);
        stv(&C[(size_t)m * N + n], acc);
    }
}

// M = W3b @ W2 (256 x 64); sb[d] = row-sum of W3b. W3: (256,512), W2: (256,64)
__global__ void prep_M(const float* __restrict__ W3, const float* __restrict__ W2,
                       float* __restrict__ Mmat, float* __restrict__ sb)
{
    int d = blockIdx.x, a = threadIdx.x;
    float s = 0.f;
    for (int j = 0; j < 256; j++)
        s += W3[d * 512 + 256 + j] * W2[j * 64 + a];
    Mmat[d * 64 + a] = s;
    if (a == 0) {
        float t = 0.f;
        for (int j = 0; j < 256; j++) t += W3[d * 512 + 256 + j];
        sb[d] = t;
    }
}

__global__ void deg_init(float* __restrict__ deg)
{
    int i = blockIdx.x * 256 + threadIdx.x;
    if (i < BN_TOT) deg[i] = 1.f;   // self loop
}

__global__ void deg_edges(const int* __restrict__ ecol, float* __restrict__ deg)
{
    int e = blockIdx.x * 256 + threadIdx.x;
    if (e < BE_TOT) {
        int b = e / EE;
        atomicAdd(&deg[b * NN + ecol[e]], 1.f);
    }
}

// One block per edge; thread t = output channel d.
__global__ void edge_scatter(const int* __restrict__ erow, const int* __restrict__ ecol,
                             const float* __restrict__ eattr, const float* __restrict__ Mmat,
                             const float* __restrict__ y1, const float* __restrict__ deg,
                             float* __restrict__ agg)
{
    int e = blockIdx.x;
    int t = threadIdx.x;
    int b = e >> 11;                 // E = 2048
    __shared__ float ea[64];
    if (t < 64) ea[t] = eattr[(size_t)e * 64 + t];
    __syncthreads();
    int rg = b * NN + erow[e];
    int cg = b * NN + ecol[e];
    float norm = rsqrtf(deg[rg] * deg[cg]);
    const float* Mr = Mmat + t * 64;
    float v = 0.f;
#pragma unroll
    for (int k = 0; k < 64; k++) v += Mr[k] * ea[k];
    v += y1[(size_t)rg * 256 + t];
    atomicAdd(&agg[(size_t)cg * 256 + t], norm * v);
}

__global__ void gcn_finalize(float* __restrict__ agg, const float* __restrict__ y1,
                             const float* __restrict__ sb, const float* __restrict__ deg,
                             const float* __restrict__ gcn_bias, const int* __restrict__ lengths)
{
    size_t idx = (size_t)blockIdx.x * 256 + threadIdx.x;   // grid = BN_TOT blocks
    int j = (int)(idx >> 8);
    int d = (int)(idx & 255);
    float dg = deg[j];
    float a  = (agg[idx] + (y1[idx] + sb[d]) / dg) / dg;
    float h  = tanhf(a + gcn_bias[d]);
    int b = j >> 9, p = j & 511;
    if (p >= lengths[b]) h = 0.f;
    agg[idx] = h;
}

__global__ void bn_stats(const float* __restrict__ X, float* __restrict__ sums,
                         float* __restrict__ sumsq, int R)
{
    int t = threadIdx.x;
    float s = 0.f, q = 0.f;
    for (int r = blockIdx.x; r < R; r += gridDim.x) {
        float v = X[(size_t)r * DD + t];
        s += v; q += v * v;
    }
    atomicAdd(&sums[t], s);
    atomicAdd(&sumsq[t], q);
}

__global__ void bn_apply(float* __restrict__ X, const float* __restrict__ sums,
                         const float* __restrict__ sumsq, const float* __restrict__ g,
                         const float* __restrict__ bt, int R)
{
    size_t idx = (size_t)blockIdx.x * 256 + threadIdx.x;
    int d = (int)(idx & 255);
    float invR = 1.f / (float)R;
    float m   = sums[d] * invR;
    float var = sumsq[d] * invR - m * m;
    X[idx] = (X[idx] - m) * rsqrtf(fmaxf(var, 0.f) + EPSF) * g[d] + bt[d];
}

// One block per (b, h, q) attention row. qkv: (B*N, 768) bf16 = [q|k|v].
__global__ void attn_kernel(const bf16* __restrict__ qkv, float* __restrict__ out)
{
    int idx = blockIdx.x;
    int q = idx & 511;
    int h = (idx >> 9) & 3;
    int b = idx >> 11;
    int t = threadIdx.x;   // 256
    __shared__ float qv[64];
    __shared__ float sc[512];
    __shared__ float red[256];
    const bf16* base = qkv + (size_t)b * NN * 768;
    if (t < 64) qv[t] = tf(base[(size_t)q * 768 + h * 64 + t]);
    __syncthreads();
    for (int k = t; k < 512; k += 256) {
        const bf16* kv = base + (size_t)k * 768 + 256 + h * 64;
        float s = 0.f;
#pragma unroll
        for (int d = 0; d < 64; d++) s += qv[d] * tf(kv[d]);
        sc[k] = s * 0.125f;
    }
    __syncthreads();
    float m = -1e30f;
    for (int k = t; k < 512; k += 256) m = fmaxf(m, sc[k]);
    red[t] = m; __syncthreads();
    for (int s = 128; s > 0; s >>= 1) { if (t < s) red[t] = fmaxf(red[t], red[t + s]); __syncthreads(); }
    m = red[0]; __syncthreads();
    float sum = 0.f;
    for (int k = t; k < 512; k += 256) { float e = __expf(sc[k] - m); sc[k] = e; sum += e; }
    red[t] = sum; __syncthreads();
    for (int s = 128; s > 0; s >>= 1) { if (t < s) red[t] += red[t + s]; __syncthreads(); }
    float inv = 1.f / red[0];
    __syncthreads();
    int d  = t & 63;
    int ch = t >> 6;
    float acc = 0.f;
    for (int k = ch * 128; k < (ch + 1) * 128; k++)
        acc += sc[k] * tf(base[(size_t)k * 768 + 512 + h * 64 + d]);
    red[t] = acc; __syncthreads();
    if (t < 64) {
        float r = red[t] + red[t + 64] + red[t + 128] + red[t + 192];
        out[((size_t)b * NN + q) * 256 + h * 64 + t] = r * inv;
    }
}

// out = LN(X + Y); one block per row of 256.
__global__ void add_ln_kernel(const float* __restrict__ X, const float* __restrict__ Y,
                              const float* __restrict__ g, const float* __restrict__ bt,
                              float* __restrict__ out)
{
    int row = blockIdx.x;
    int t   = threadIdx.x;
    size_t idx = (size_t)row * DD + t;
    float v = X[idx] + Y[idx];
    __shared__ float red[DD];
    red[t] = v; __syncthreads();
    for (int s = 128; s > 0; s >>= 1) { if (t < s) red[t] += red[t + s]; __syncthreads(); }
    float m = red[0] * (1.f / DD);
    __syncthreads();
    float d = v - m;
    red[t] = d * d; __syncthreads();
    for (int s = 128; s > 0; s >>= 1) { if (t < s) red[t] += red[t + s]; __syncthreads(); }
    float var = red[0] * (1.f / DD);
    out[idx] = d * rsqrtf(var + EPSF) * g[t] + bt[t];
}

__global__ void pool_kernel(const float* __restrict__ enc, const int* __restrict__ lengths,
                            float* __restrict__ poolbuf)
{
    int b = blockIdx.x;
    int t = threadIdx.x;   // channel
    int L = lengths[b];
    if (L < 1) L = 1;
    const float* p = enc + (size_t)b * NN * DD + t;
    float s = 0.f, mx = -1e30f;
    for (int n = 0; n < NN; n++) {
        float v = p[(size_t)n * DD];
        s += v;
        if (n < L) mx = fmaxf(mx, v);
    }
    poolbuf[b * 512 + t]       = mx;
    poolbuf[b * 512 + 256 + t] = s / (float)L;
}

__global__ void head_kernel(const float* __restrict__ poolbuf, const float* __restrict__ lin_w,
                            const float* __restrict__ lin_b, const float* __restrict__ g,
                            const float* __restrict__ bt, float* __restrict__ out)
{
    int b = threadIdx.x;   // 64
    float r0 = lin_b[0], r1 = lin_b[1];
    for (int k = 0; k < 512; k++) {
        float p = poolbuf[b * 512 + k];
        r0 += p * lin_w[k];
        r1 += p * lin_w[512 + k];
    }
    __shared__ float s0[64], s1[64], mstat[4];
    s0[b] = r0; s1[b] = r1; __syncthreads();
    if (b == 0) {
        float a0 = 0, a1 = 0, q0 = 0, q1 = 0;
        for (int i = 0; i < 64; i++) { a0 += s0[i]; a1 += s1[i]; }
        a0 *= (1.f / 64.f); a1 *= (1.f / 64.f);
        for (int i = 0; i < 64; i++) {
            float d0 = s0[i] - a0, d1 = s1[i] - a1;
            q0 += d0 * d0; q1 += d1 * d1;
        }
        mstat[0] = a0; mstat[1] = a1; mstat[2] = q0 * (1.f / 64.f); mstat[3] = q1 * (1.f / 64.f);
    }
    __syncthreads();
    float z0 = (r0 - mstat[0]) * rsqrtf(mstat[2] + EPSF) * g[0] + bt[0];
    float z1 = (r1 - mstat[1]) * rsqrtf(mstat[3] + EPSF) * g[1] + bt[1];
    float mx = fmaxf(z0, z1);
    float e0 = __expf(z0 - mx), e1 = __expf(z1 - mx);
    float inv = 1.f / (e0 + e1);
    out[b * 2 + 0] = e0 * inv;
    out[b * 2 + 1] = e1 * inv;
}

extern "C" void kernel_launch(void* const* d_in, const int* in_sizes, int n_in,
                              void* d_out, int out_size, void* d_ws, size_t ws_size,
                              hipStream_t stream)
{
    (void)in_sizes; (void)n_in; (void)out_size; (void)ws_size;
    const float* x          = (const float*)d_in[0];
    const float* edge_attr  = (const float*)d_in[1];
    const float* W1         = (const float*)d_in[5];
    const float* W2         = (const float*)d_in[6];
    const float* W3         = (const float*)d_in[7];
    const float* b3         = (const float*)d_in[8];
    const float* gcn_bias   = (const float*)d_in[9];
    const float* bn1_g      = (const float*)d_in[10];
    const float* bn1_b      = (const float*)d_in[11];
    const float* in_proj_w  = (const float*)d_in[12];
    const float* in_proj_b  = (const float*)d_in[13];
    const float* out_proj_w = (const float*)d_in[14];
    const float* out_proj_b = (const float*)d_in[15];
    const float* ln1_g      = (const float*)d_in[16];
    const float* ln1_b      = (const float*)d_in[17];
    const float* lin1_w     = (const float*)d_in[18];
    const float* lin1_b     = (const float*)d_in[19];
    const float* lin2_w     = (const float*)d_in[20];
    const float* lin2_b     = (const float*)d_in[21];
    const float* ln2_g      = (const float*)d_in[22];
    const float* ln2_b      = (const float*)d_in[23];
    const float* bn2_g      = (const float*)d_in[24];
    const float* bn2_b      = (const float*)d_in[25];
    const float* lin_w      = (const float*)d_in[26];
    const float* lin_b      = (const float*)d_in[27];
    const float* bn3_g      = (const float*)d_in[28];
    const float* bn3_b      = (const float*)d_in[29];

    // ---- Workspace layout: ~162 MB ----
    char* p = (char*)d_ws;
    bf16*  big   = (bf16*)p;  p += (size_t)BN_TOT * 1024 * 2;   // 64 MB: qkv then ffa
    float* bufA  = (float*)p; p += (size_t)BN_TOT * 256 * 4;    // 32 MB
    float* bufB  = (float*)p; p += (size_t)BN_TOT * 256 * 4;    // 32 MB
    float* bufC  = (float*)p; p += (size_t)BN_TOT * 256 * 4;    // 32 MB
    float* deg   = (float*)p; p += (size_t)BN_TOT * 4;
    float* Mmat  = (float*)p; p += 256 * 64 * 4;
    float* sb    = (float*)p; p += 1024;
    float* stats = (float*)p; p += 4 * 256 * 4;
    float* poolbuf=(float*)p; p += 64 * 512 * 4;
    int*   flags = (int*)p;   p += 256;
    int*   erc   = (int*)p;   p += BE_TOT * 4;                  // canonical edge_row
    int*   ecc   = (int*)p;   p += BE_TOT * 4;                  // canonical edge_col
    int*   lenc  = (int*)p;   p += 256;                         // canonical lengths

    // ---- int dtype detection + canonicalization ----
    detect_kernel<<<1, 1, 0, stream>>>((const int*)d_in[4], flags);
    conv_i<<<(BE_TOT + 255) / 256, 256, 0, stream>>>(d_in[2], erc, BE_TOT, flags);
    conv_i<<<(BE_TOT + 255) / 256, 256, 0, stream>>>(d_in[3], ecc, BE_TOT, flags);
    conv_i<<<1, 64, 0, stream>>>(d_in[4], lenc, BB, flags);

    float* xs      = bufA;
    float* y1      = bufB;
    float* agg     = bufA;    // xs dead after y1 GEMM; zeroed stream-ordered below
    bf16*  qkv     = big;
    float* attnout = bufB;    // y1 dead after gcn_finalize
    float* attnp   = bufC;
    float* h1      = bufB;    // attnout dead after out_proj GEMM
    bf16*  ffa     = big;     // qkv dead after attn_kernel
    float* ffb     = bufA;    // h dead after add_ln #1
    float* h2      = bufC;    // attnp dead after add_ln #1

    hipMemsetAsync(stats, 0, 4 * 256 * 4, stream);

    dim3 t16(16, 16);

    prep_M<<<256, 64, 0, stream>>>(W3, W2, Mmat, sb);
    deg_init<<<BN_TOT / 256, 256, 0, stream>>>(deg);
    deg_edges<<<BE_TOT / 256, 256, 0, stream>>>(ecc, deg);

    // xs = x @ W1.T
    gemm_kernel<float, float><<<dim3(256 / 16, BN_TOT / 16), t16, 0, stream>>>(
        x, W1, nullptr, xs, BN_TOT, 256, FINK, FINK, 0);
    // y1 = xs @ W3a.T + b3  (W3a = W3[:, :256], ldw = 512)
    gemm_kernel<float, float><<<dim3(256 / 16, BN_TOT / 16), t16, 0, stream>>>(
        xs, W3, b3, y1, BN_TOT, 256, 256, 512, 0);

    hipMemsetAsync(agg, 0, (size_t)BN_TOT * 256 * 4, stream);   // agg aliases xs

    edge_scatter<<<BE_TOT, 256, 0, stream>>>(erc, ecc, edge_attr, Mmat, y1, deg, agg);
    gcn_finalize<<<BN_TOT, 256, 0, stream>>>(agg, y1, sb, deg, gcn_bias, lenc);

    bn_stats<<<512, 256, 0, stream>>>(agg, stats, stats + 256, BN_TOT);
    bn_apply<<<BN_TOT, 256, 0, stream>>>(agg, stats, stats + 256, bn1_g, bn1_b, BN_TOT);

    gemm_kernel<float, bf16><<<dim3(768 / 16, BN_TOT / 16), t16, 0, stream>>>(
        agg, in_proj_w, in_proj_b, qkv, BN_TOT, 768, 256, 256, 0);

    attn_kernel<<<BB * NHH * NN, 256, 0, stream>>>(qkv, attnout);

    gemm_kernel<float, float><<<dim3(256 / 16, BN_TOT / 16), t16, 0, stream>>>(
        attnout, out_proj_w, out_proj_b, attnp, BN_TOT, 256, 256, 256, 0);

    add_ln_kernel<<<BN_TOT, 256, 0, stream>>>(agg, attnp, ln1_g, ln1_b, h1);

    gemm_kernel<float, bf16><<<dim3(1024 / 16, BN_TOT / 16), t16, 0, stream>>>(
        h1, lin1_w, lin1_b, ffa, BN_TOT, 1024, 256, 256, 1);
    gemm_kernel<bf16, float><<<dim3(256 / 16, BN_TOT / 16), t16, 0, stream>>>(
        ffa, lin2_w, lin2_b, ffb, BN_TOT, 256, 1024, 1024, 0);

    add_ln_kernel<<<BN_TOT, 256, 0, stream>>>(h1, ffb, ln2_g, ln2_b, h2);

    bn_stats<<<512, 256, 0, stream>>>(h2, stats + 512, stats + 768, BN_TOT);
    bn_apply<<<BN_TOT, 256, 0, stream>>>(h2, stats + 512, stats + 768, bn2_g, bn2_b, BN_TOT);

    pool_kernel<<<64, 256, 0, stream>>>(h2, lenc, poolbuf);
    head_kernel<<<1, 64, 0, stream>>>(poolbuf, lin_w, lin_b, bn3_g, bn3_b, (float*)d_out);
}

// Round 6
// 2524.822 us; speedup vs baseline: 3.3556x; 3.3556x over previous
//
#include <hip/hip_runtime.h>
#include <hip/hip_bf16.h>

// Shapes
#define BB   64
#define NN   512
#define EE   2048
#define FINK 300
#define DD   256
#define BN_TOT (BB*NN)    // 32768
#define BE_TOT (BB*EE)    // 131072
#define EPSF 1e-5f

using bf16 = __hip_bfloat16;
typedef unsigned short u16;
typedef __attribute__((ext_vector_type(8))) short short8;
typedef __attribute__((ext_vector_type(4))) float f32x4;

__device__ __forceinline__ float tf(float x) { return x; }
__device__ __forceinline__ float tf(bf16 x)  { return __bfloat162float(x); }
__device__ __forceinline__ void  stv(float* p, float v) { *p = v; }
__device__ __forceinline__ void  stv(bf16*  p, float v) { *p = __float2bfloat16(v); }

__device__ __forceinline__ u16 f2bu(float f) {
    bf16 b = __float2bfloat16(f);
    return *(u16*)&b;
}
__device__ __forceinline__ float blo(unsigned u) {
    unsigned x = u << 16; return *(float*)&x;
}
__device__ __forceinline__ float bhi(unsigned u) {
    unsigned x = u & 0xffff0000u; return *(float*)&x;
}

// Int dtype probe: lengths[1] as int32 is in [256,512] iff int32 storage;
// it is the zero hi-word of lengths[0] iff int64 (LE).
__global__ void detect_kernel(const int* __restrict__ lengths, int* __restrict__ flags)
{
    flags[1] = (lengths[1] == 0) ? 1 : 0;
}

__global__ void conv_i(const void* __restrict__ src, int* __restrict__ dst, int n,
                       const int* __restrict__ flags)
{
    int i = blockIdx.x * 256 + threadIdx.x;
    if (i >= n) return;
    const int* s = (const int*)src;
    dst[i] = s[flags[1] ? (i << 1) : i];
}

// ---------------------------------------------------------------------------
// MFMA GEMM: C[m,n] = sum_k A[m,k]*W[n*ldw+k] (+bias,+relu)
// Tile 128x128, 4 waves (2x2 of 64x64), K-step 32, bf16 LDS staging.
// A: f32 or bf16 row-major (M,K); W: f32 row-major (N,ldw); C: f32 or bf16.
// M, N multiples of 128. K arbitrary (zero-padded in LDS).
// Fragment layouts (HW-verified m89/m91/m120):
//   A/B: lane holds row (lane&15), k = (lane>>4)*8 + j  (8 bf16 = 1 b128)
//   C/D: col = lane&15, row = (lane>>4)*4 + reg
// ---------------------------------------------------------------------------
template<typename TA, typename TC, int RELU>
__global__ __launch_bounds__(256)
void gemm_mfma(const TA* __restrict__ A, const float* __restrict__ W,
               const float* __restrict__ bias, TC* __restrict__ C,
               int M, int N, int K, int ldw)
{
    __shared__ u16 As[128][40];   // +8 pad
    __shared__ u16 Ws[128][40];

    const int m0 = blockIdx.y * 128;
    const int n0 = blockIdx.x * 128;
    const int tid  = threadIdx.x;
    const int lane = tid & 63;
    const int wv   = tid >> 6;           // 0..3
    const int mb   = (wv >> 1) * 64;
    const int nb   = (wv & 1) * 64;
    const int fr   = lane & 15;
    const int q8   = (lane >> 4) * 8;

    const int srow = tid >> 3;           // 0..31 (staging row base)
    const int sc4  = (tid & 7) * 4;      // k sub-offset

    f32x4 acc[4][4];
#pragma unroll
    for (int i = 0; i < 4; i++)
#pragma unroll
        for (int j = 0; j < 4; j++) acc[i][j] = (f32x4){0.f, 0.f, 0.f, 0.f};

    for (int k0 = 0; k0 < K; k0 += 32) {
        __syncthreads();
        // stage A and W tiles (each thread: 4 rows x 4 elems)
#pragma unroll
        for (int i = 0; i < 4; i++) {
            int r = srow + i * 32;
            const TA* ap = A + (size_t)(m0 + r) * K + k0 + sc4;
            const float* wp = W + (size_t)(n0 + r) * ldw + k0 + sc4;
            if (k0 + sc4 + 3 < K) {
                As[r][sc4+0] = f2bu(tf(ap[0])); As[r][sc4+1] = f2bu(tf(ap[1]));
                As[r][sc4+2] = f2bu(tf(ap[2])); As[r][sc4+3] = f2bu(tf(ap[3]));
                Ws[r][sc4+0] = f2bu(wp[0]); Ws[r][sc4+1] = f2bu(wp[1]);
                Ws[r][sc4+2] = f2bu(wp[2]); Ws[r][sc4+3] = f2bu(wp[3]);
            } else {
#pragma unroll
                for (int u = 0; u < 4; u++) {
                    int kk = k0 + sc4 + u;
                    As[r][sc4+u] = (kk < K) ? f2bu(tf(ap[u])) : 0;
                    Ws[r][sc4+u] = (kk < K) ? f2bu(wp[u]) : 0;
                }
            }
        }
        __syncthreads();

        short8 af[4], bf[4];
#pragma unroll
        for (int i = 0; i < 4; i++) af[i] = *(const short8*)&As[mb + i*16 + fr][q8];
#pragma unroll
        for (int j = 0; j < 4; j++) bf[j] = *(const short8*)&Ws[nb + j*16 + fr][q8];
#pragma unroll
        for (int i = 0; i < 4; i++)
#pragma unroll
            for (int j = 0; j < 4; j++)
                acc[i][j] = __builtin_amdgcn_mfma_f32_16x16x32_bf16(af[i], bf[j], acc[i][j], 0, 0, 0);
    }

    // epilogue
#pragma unroll
    for (int i = 0; i < 4; i++) {
#pragma unroll
        for (int j = 0; j < 4; j++) {
            int gn = n0 + nb + j * 16 + fr;
            float bv = bias ? bias[gn] : 0.f;
#pragma unroll
            for (int r = 0; r < 4; r++) {
                int gm = m0 + mb + i * 16 + (lane >> 4) * 4 + r;
                float v = acc[i][j][r] + bv;
                if (RELU) v = fmaxf(v, 0.f);
                stv(&C[(size_t)gm * N + gn], v);
            }
        }
    }
}

// M = W3b @ W2 (256 x 64); sb[d] = row-sum of W3b. W3: (256,512), W2: (256,64)
__global__ void prep_M(const float* __restrict__ W3, const float* __restrict__ W2,
                       float* __restrict__ Mmat, float* __restrict__ sb)
{
    int d = blockIdx.x, a = threadIdx.x;
    float s = 0.f;
    for (int j = 0; j < 256; j++)
        s += W3[d * 512 + 256 + j] * W2[j * 64 + a];
    Mmat[d * 64 + a] = s;
    if (a == 0) {
        float t = 0.f;
        for (int j = 0; j < 256; j++) t += W3[d * 512 + 256 + j];
        sb[d] = t;
    }
}

__global__ void deg_init(float* __restrict__ deg)
{
    int i = blockIdx.x * 256 + threadIdx.x;
    if (i < BN_TOT) deg[i] = 1.f;
}

__global__ void deg_edges(const int* __restrict__ ecol, float* __restrict__ deg)
{
    int e = blockIdx.x * 256 + threadIdx.x;
    if (e < BE_TOT) {
        int b = e / EE;
        atomicAdd(&deg[b * NN + ecol[e]], 1.f);
    }
}

__global__ void edge_scatter(const int* __restrict__ erow, const int* __restrict__ ecol,
                             const float* __restrict__ eattr, const float* __restrict__ Mmat,
                             const float* __restrict__ y1, const float* __restrict__ deg,
                             float* __restrict__ agg)
{
    int e = blockIdx.x;
    int t = threadIdx.x;
    int b = e >> 11;
    __shared__ float ea[64];
    if (t < 64) ea[t] = eattr[(size_t)e * 64 + t];
    __syncthreads();
    int rg = b * NN + erow[e];
    int cg = b * NN + ecol[e];
    float norm = rsqrtf(deg[rg] * deg[cg]);
    const float* Mr = Mmat + t * 64;
    float v = 0.f;
#pragma unroll
    for (int k = 0; k < 64; k++) v += Mr[k] * ea[k];
    v += y1[(size_t)rg * 256 + t];
    atomicAdd(&agg[(size_t)cg * 256 + t], norm * v);
}

__global__ void gcn_finalize(float* __restrict__ agg, const float* __restrict__ y1,
                             const float* __restrict__ sb, const float* __restrict__ deg,
                             const float* __restrict__ gcn_bias, const int* __restrict__ lengths)
{
    size_t idx = (size_t)blockIdx.x * 256 + threadIdx.x;
    int j = (int)(idx >> 8);
    int d = (int)(idx & 255);
    float dg = deg[j];
    float a  = (agg[idx] + (y1[idx] + sb[d]) / dg) / dg;
    float h  = tanhf(a + gcn_bias[d]);
    int b = j >> 9, p = j & 511;
    if (p >= lengths[b]) h = 0.f;
    agg[idx] = h;
}

__global__ void bn_stats(const float* __restrict__ X, float* __restrict__ sums,
                         float* __restrict__ sumsq, int R)
{
    int t = threadIdx.x;
    float s = 0.f, q = 0.f;
    for (int r = blockIdx.x; r < R; r += gridDim.x) {
        float v = X[(size_t)r * DD + t];
        s += v; q += v * v;
    }
    atomicAdd(&sums[t], s);
    atomicAdd(&sumsq[t], q);
}

__global__ void bn_apply(float* __restrict__ X, const float* __restrict__ sums,
                         const float* __restrict__ sumsq, const float* __restrict__ g,
                         const float* __restrict__ bt, int R)
{
    size_t idx = (size_t)blockIdx.x * 256 + threadIdx.x;
    int d = (int)(idx & 255);
    float invR = 1.f / (float)R;
    float m   = sums[d] * invR;
    float var = sumsq[d] * invR - m * m;
    X[idx] = (X[idx] - m) * rsqrtf(fmaxf(var, 0.f) + EPSF) * g[d] + bt[d];
}

// ---------------------------------------------------------------------------
// Attention: one block per (b,h); 512 threads (8 waves).
// K rows in registers (thread k owns K-row k); V in LDS transposed bf16
// (row stride 516 -> b64 reads conflict-free); Q-tile (8 rows) in LDS f32;
// P stored bf16; 64 q-tiles per block.
// ---------------------------------------------------------------------------
__global__ __launch_bounds__(512)
void attn_kernel(const bf16* __restrict__ qkv, float* __restrict__ out)
{
    const int b = blockIdx.x >> 2;
    const int h = blockIdx.x & 3;
    const int tid = threadIdx.x;          // 0..511
    const int wv  = tid >> 6;             // wave 0..7
    const int ln  = tid & 63;

    __shared__ u16   Vt[64][516];         // Vt[d][k], 66.0 KB
    __shared__ float qsf[8][68];          // Q tile f32
    __shared__ float scf[8][512];         // raw scores
    __shared__ u16   Pb[8][520];          // P bf16
    __shared__ float invs[8];

    const u16* qb = (const u16*)qkv;
    const size_t rowbase = ((size_t)(b * NN + tid)) * 768;

    // K row tid -> registers
    float kreg[64];
    {
        const uint4* kp = (const uint4*)(qb + rowbase + 256 + h * 64);
#pragma unroll
        for (int c = 0; c < 8; c++) {
            uint4 u = kp[c];
            kreg[c*8+0] = blo(u.x); kreg[c*8+1] = bhi(u.x);
            kreg[c*8+2] = blo(u.y); kreg[c*8+3] = bhi(u.y);
            kreg[c*8+4] = blo(u.z); kreg[c*8+5] = bhi(u.z);
            kreg[c*8+6] = blo(u.w); kreg[c*8+7] = bhi(u.w);
        }
        // V row tid -> Vt[:, tid]
        const uint4* vp = (const uint4*)(qb + rowbase + 512 + h * 64);
#pragma unroll
        for (int c = 0; c < 8; c++) {
            uint4 u = vp[c];
            Vt[c*8+0][tid] = (u16)(u.x & 0xffff); Vt[c*8+1][tid] = (u16)(u.x >> 16);
            Vt[c*8+2][tid] = (u16)(u.y & 0xffff); Vt[c*8+3][tid] = (u16)(u.y >> 16);
            Vt[c*8+4][tid] = (u16)(u.z & 0xffff); Vt[c*8+5][tid] = (u16)(u.z >> 16);
            Vt[c*8+6][tid] = (u16)(u.w & 0xffff); Vt[c*8+7][tid] = (u16)(u.w >> 16);
        }
    }
    __syncthreads();

    const int qq = tid >> 6;              // for loads / PV: q row 0..7
    const int dd = tid & 63;              // d channel

    for (int t0 = 0; t0 < NN; t0 += 8) {
        // load Q tile (8 x 64)
        qsf[qq][dd] = blo((unsigned)qb[((size_t)(b * NN + t0 + qq)) * 768 + h * 64 + dd] << 16 >> 16 ? 0u : 0u), // placeholder avoided below
        qsf[qq][dd] = [&]{ unsigned u = qb[((size_t)(b * NN + t0 + qq)) * 768 + h * 64 + dd]; unsigned x = u << 16; return *(float*)&x; }();
        __syncthreads();

        // QK: thread k computes scores for its k across 8 q
#pragma unroll
        for (int q = 0; q < 8; q++) {
            const float* Qr = qsf[q];
            float s = 0.f;
#pragma unroll
            for (int j = 0; j < 64; j += 4) {
                float4 qv = *(const float4*)(Qr + j);
                s += qv.x * kreg[j] + qv.y * kreg[j+1] + qv.z * kreg[j+2] + qv.w * kreg[j+3];
            }
            scf[q][tid] = s * 0.125f;
        }
        __syncthreads();

        // softmax: wave wv handles row wv
        {
            float vv[8];
            float m = -1e30f;
#pragma unroll
            for (int i = 0; i < 8; i++) { vv[i] = scf[wv][ln + 64*i]; m = fmaxf(m, vv[i]); }
#pragma unroll
            for (int off = 32; off > 0; off >>= 1) m = fmaxf(m, __shfl_xor(m, off));
            float ssum = 0.f;
#pragma unroll
            for (int i = 0; i < 8; i++) {
                float e = __expf(vv[i] - m);
                Pb[wv][ln + 64*i] = f2bu(e);
                ssum += e;
            }
#pragma unroll
            for (int off = 32; off > 0; off >>= 1) ssum += __shfl_xor(ssum, off);
            if (ln == 0) invs[wv] = 1.f / ssum;
        }
        __syncthreads();

        // PV: thread (q=qq, d=dd): acc = sum_k P[q][k] * Vt[d][k]
        {
            const u16* Pr = &Pb[qq][0];
            const u16* Vr = &Vt[dd][0];
            float acc = 0.f;
#pragma unroll 8
            for (int c = 0; c < 64; c++) {
                uint4 pv = *(const uint4*)(Pr + c*8);
                uint2 v0 = *(const uint2*)(Vr + c*8);
                uint2 v1 = *(const uint2*)(Vr + c*8 + 4);
                acc += blo(pv.x) * blo(v0.x) + bhi(pv.x) * bhi(v0.x)
                     + blo(pv.y) * blo(v0.y) + bhi(pv.y) * bhi(v0.y)
                     + blo(pv.z) * blo(v1.x) + bhi(pv.z) * bhi(v1.x)
                     + blo(pv.w) * blo(v1.y) + bhi(pv.w) * bhi(v1.y);
            }
            out[((size_t)(b * NN + t0 + qq)) * 256 + h * 64 + dd] = acc * invs[qq];
        }
        __syncthreads();
    }
}

// out = LN(X + Y); one block per row of 256.
__global__ void add_ln_kernel(const float* __restrict__ X, const float* __restrict__ Y,
                              const float* __restrict__ g, const float* __restrict__ bt,
                              float* __restrict__ out)
{
    int row = blockIdx.x;
    int t   = threadIdx.x;
    size_t idx = (size_t)row * DD + t;
    float v = X[idx] + Y[idx];
    __shared__ float red[DD];
    red[t] = v; __syncthreads();
    for (int s = 128; s > 0; s >>= 1) { if (t < s) red[t] += red[t + s]; __syncthreads(); }
    float m = red[0] * (1.f / DD);
    __syncthreads();
    float d = v - m;
    red[t] = d * d; __syncthreads();
    for (int s = 128; s > 0; s >>= 1) { if (t < s) red[t] += red[t + s]; __syncthreads(); }
    float var = red[0] * (1.f / DD);
    out[idx] = d * rsqrtf(var + EPSF) * g[t] + bt[t];
}

__global__ void pool_kernel(const float* __restrict__ enc, const int* __restrict__ lengths,
                            float* __restrict__ poolbuf)
{
    int b = blockIdx.x;
    int t = threadIdx.x;
    int L = lengths[b];
    if (L < 1) L = 1;
    const float* p = enc + (size_t)b * NN * DD + t;
    float s = 0.f, mx = -1e30f;
    for (int n = 0; n < NN; n++) {
        float v = p[(size_t)n * DD];
        s += v;
        if (n < L) mx = fmaxf(mx, v);
    }
    poolbuf[b * 512 + t]       = mx;
    poolbuf[b * 512 + 256 + t] = s / (float)L;
}

__global__ void head_kernel(const float* __restrict__ poolbuf, const float* __restrict__ lin_w,
                            const float* __restrict__ lin_b, const float* __restrict__ g,
                            const float* __restrict__ bt, float* __restrict__ out)
{
    int b = threadIdx.x;
    float r0 = lin_b[0], r1 = lin_b[1];
    for (int k = 0; k < 512; k++) {
        float p = poolbuf[b * 512 + k];
        r0 += p * lin_w[k];
        r1 += p * lin_w[512 + k];
    }
    __shared__ float s0[64], s1[64], mstat[4];
    s0[b] = r0; s1[b] = r1; __syncthreads();
    if (b == 0) {
        float a0 = 0, a1 = 0, q0 = 0, q1 = 0;
        for (int i = 0; i < 64; i++) { a0 += s0[i]; a1 += s1[i]; }
        a0 *= (1.f / 64.f); a1 *= (1.f / 64.f);
        for (int i = 0; i < 64; i++) {
            float d0 = s0[i] - a0, d1 = s1[i] - a1;
            q0 += d0 * d0; q1 += d1 * d1;
        }
        mstat[0] = a0; mstat[1] = a1; mstat[2] = q0 * (1.f / 64.f); mstat[3] = q1 * (1.f / 64.f);
    }
    __syncthreads();
    float z0 = (r0 - mstat[0]) * rsqrtf(mstat[2] + EPSF) * g[0] + bt[0];
    float z1 = (r1 - mstat[1]) * rsqrtf(mstat[3] + EPSF) * g[1] + bt[1];
    float mx = fmaxf(z0, z1);
    float e0 = __expf(z0 - mx), e1 = __expf(z1 - mx);
    float inv = 1.f / (e0 + e1);
    out[b * 2 + 0] = e0 * inv;
    out[b * 2 + 1] = e1 * inv;
}

extern "C" void kernel_launch(void* const* d_in, const int* in_sizes, int n_in,
                              void* d_out, int out_size, void* d_ws, size_t ws_size,
                              hipStream_t stream)
{
    (void)in_sizes; (void)n_in; (void)out_size; (void)ws_size;
    const float* x          = (const float*)d_in[0];
    const float* edge_attr  = (const float*)d_in[1];
    const float* W1         = (const float*)d_in[5];
    const float* W2         = (const float*)d_in[6];
    const float* W3         = (const float*)d_in[7];
    const float* b3         = (const float*)d_in[8];
    const float* gcn_bias   = (const float*)d_in[9];
    const float* bn1_g      = (const float*)d_in[10];
    const float* bn1_b      = (const float*)d_in[11];
    const float* in_proj_w  = (const float*)d_in[12];
    const float* in_proj_b  = (const float*)d_in[13];
    const float* out_proj_w = (const float*)d_in[14];
    const float* out_proj_b = (const float*)d_in[15];
    const float* ln1_g      = (const float*)d_in[16];
    const float* ln1_b      = (const float*)d_in[17];
    const float* lin1_w     = (const float*)d_in[18];
    const float* lin1_b     = (const float*)d_in[19];
    const float* lin2_w     = (const float*)d_in[20];
    const float* lin2_b     = (const float*)d_in[21];
    const float* ln2_g      = (const float*)d_in[22];
    const float* ln2_b      = (const float*)d_in[23];
    const float* bn2_g      = (const float*)d_in[24];
    const float* bn2_b      = (const float*)d_in[25];
    const float* lin_w      = (const float*)d_in[26];
    const float* lin_b      = (const float*)d_in[27];
    const float* bn3_g      = (const float*)d_in[28];
    const float* bn3_b      = (const float*)d_in[29];

    // ---- Workspace layout: ~162 MB ----
    char* p = (char*)d_ws;
    bf16*  big   = (bf16*)p;  p += (size_t)BN_TOT * 1024 * 2;   // 64 MB: qkv then ffa
    float* bufA  = (float*)p; p += (size_t)BN_TOT * 256 * 4;
    float* bufB  = (float*)p; p += (size_t)BN_TOT * 256 * 4;
    float* bufC  = (float*)p; p += (size_t)BN_TOT * 256 * 4;
    float* deg   = (float*)p; p += (size_t)BN_TOT * 4;
    float* Mmat  = (float*)p; p += 256 * 64 * 4;
    float* sb    = (float*)p; p += 1024;
    float* stats = (float*)p; p += 4 * 256 * 4;
    float* poolbuf=(float*)p; p += 64 * 512 * 4;
    int*   flags = (int*)p;   p += 256;
    int*   erc   = (int*)p;   p += BE_TOT * 4;
    int*   ecc   = (int*)p;   p += BE_TOT * 4;
    int*   lenc  = (int*)p;   p += 256;

    detect_kernel<<<1, 1, 0, stream>>>((const int*)d_in[4], flags);
    conv_i<<<(BE_TOT + 255) / 256, 256, 0, stream>>>(d_in[2], erc, BE_TOT, flags);
    conv_i<<<(BE_TOT + 255) / 256, 256, 0, stream>>>(d_in[3], ecc, BE_TOT, flags);
    conv_i<<<1, 64, 0, stream>>>(d_in[4], lenc, BB, flags);

    float* xs      = bufA;
    float* y1      = bufB;
    float* agg     = bufA;    // xs dead after y1 GEMM
    bf16*  qkv     = big;
    float* attnout = bufB;    // y1 dead after gcn_finalize
    float* attnp   = bufC;
    float* h1      = bufB;
    bf16*  ffa     = big;     // qkv dead after attn_kernel
    float* ffb     = bufA;
    float* h2      = bufC;

    hipMemsetAsync(stats, 0, 4 * 256 * 4, stream);

    prep_M<<<256, 64, 0, stream>>>(W3, W2, Mmat, sb);
    deg_init<<<BN_TOT / 256, 256, 0, stream>>>(deg);
    deg_edges<<<BE_TOT / 256, 256, 0, stream>>>(ecc, deg);

    // xs = x @ W1.T   (K=300 padded)
    gemm_mfma<float, float, 0><<<dim3(256/128, BN_TOT/128), 256, 0, stream>>>(
        x, W1, nullptr, xs, BN_TOT, 256, FINK, FINK);
    // y1 = xs @ W3a.T + b3  (ldw=512)
    gemm_mfma<float, float, 0><<<dim3(256/128, BN_TOT/128), 256, 0, stream>>>(
        xs, W3, b3, y1, BN_TOT, 256, 256, 512);

    hipMemsetAsync(agg, 0, (size_t)BN_TOT * 256 * 4, stream);   // agg aliases xs

    edge_scatter<<<BE_TOT, 256, 0, stream>>>(erc, ecc, edge_attr, Mmat, y1, deg, agg);
    gcn_finalize<<<BN_TOT, 256, 0, stream>>>(agg, y1, sb, deg, gcn_bias, lenc);

    bn_stats<<<512, 256, 0, stream>>>(agg, stats, stats + 256, BN_TOT);
    bn_apply<<<BN_TOT, 256, 0, stream>>>(agg, stats, stats + 256, bn1_g, bn1_b, BN_TOT);

    gemm_mfma<float, bf16, 0><<<dim3(768/128, BN_TOT/128), 256, 0, stream>>>(
        agg, in_proj_w, in_proj_b, qkv, BN_TOT, 768, 256, 256);

    attn_kernel<<<BB * 4, 512, 0, stream>>>(qkv, attnout);

    gemm_mfma<float, float, 0><<<dim3(256/128, BN_TOT/128), 256, 0, stream>>>(
        attnout, out_proj_w, out_proj_b, attnp, BN_TOT, 256, 256, 256);

    add_ln_kernel<<<BN_TOT, 256, 0, stream>>>(agg, attnp, ln1_g, ln1_b, h1);

    gemm_mfma<float, bf16, 1><<<dim3(1024/128, BN_TOT/128), 256, 0, stream>>>(
        h1, lin1_w, lin1_b, ffa, BN_TOT, 1024, 256, 256);
    gemm_mfma<bf16, float, 0><<<dim3(256/128, BN_TOT/128), 256, 0, stream>>>(
        ffa, lin2_w, lin2_b, ffb, BN_TOT, 256, 1024, 1024);

    add_ln_kernel<<<BN_TOT, 256, 0, stream>>>(h1, ffb, ln2_g, ln2_b, h2);

    bn_stats<<<512, 256, 0, stream>>>(h2, stats + 512, stats + 768, BN_TOT);
    bn_apply<<<BN_TOT, 256, 0, stream>>>(h2, stats + 512, stats + 768, bn2_g, bn2_b, BN_TOT);

    pool_kernel<<<64, 256, 0, stream>>>(h2, lenc, poolbuf);
    head_kernel<<<1, 64, 0, stream>>>(poolbuf, lin_w, lin_b, bn3_g, bn3_b, (float*)d_out);
}

// Round 7
// 1628.410 us; speedup vs baseline: 5.2027x; 1.5505x over previous
//
#include <hip/hip_runtime.h>
#include <hip/hip_bf16.h>

// Shapes
#define BB   64
#define NN   512
#define EE   2048
#define FINK 300
#define DD   256
#define BN_TOT (BB*NN)    // 32768
#define BE_TOT (BB*EE)    // 131072
#define EPSF 1e-5f

using bf16 = __hip_bfloat16;
typedef unsigned short u16;
typedef __attribute__((ext_vector_type(8))) short short8;
typedef __attribute__((ext_vector_type(4))) float f32x4;

__device__ __forceinline__ float tf(float x) { return x; }
__device__ __forceinline__ float tf(bf16 x)  { return __bfloat162float(x); }
__device__ __forceinline__ void  stv(float* p, float v) { *p = v; }
__device__ __forceinline__ void  stv(bf16*  p, float v) { *p = __float2bfloat16(v); }

__device__ __forceinline__ u16 f2bu(float f) {
    bf16 b = __float2bfloat16(f);
    return *(u16*)&b;
}
__device__ __forceinline__ float blo(unsigned u) {
    unsigned x = u << 16; return *(float*)&x;
}
__device__ __forceinline__ float bhi(unsigned u) {
    unsigned x = u & 0xffff0000u; return *(float*)&x;
}

// Int dtype probe: lengths[1] as int32 is in [256,512] iff int32 storage;
// it is the zero hi-word of lengths[0] iff int64 (LE).
__global__ void detect_kernel(const int* __restrict__ lengths, int* __restrict__ flags)
{
    flags[1] = (lengths[1] == 0) ? 1 : 0;
}

__global__ void conv_i(const void* __restrict__ src, int* __restrict__ dst, int n,
                       const int* __restrict__ flags)
{
    int i = blockIdx.x * 256 + threadIdx.x;
    if (i >= n) return;
    const int* s = (const int*)src;
    dst[i] = s[flags[1] ? (i << 1) : i];
}

// ---------------------------------------------------------------------------
// MFMA GEMM: C[m,n] = sum_k A[m,k]*W[n*ldw+k] (+bias,+relu)
// Tile 128x128, 4 waves (2x2 of 64x64), K-step 32, bf16 LDS staging.
// ---------------------------------------------------------------------------
template<typename TA, typename TC, int RELU>
__global__ __launch_bounds__(256)
void gemm_mfma(const TA* __restrict__ A, const float* __restrict__ W,
               const float* __restrict__ bias, TC* __restrict__ C,
               int M, int N, int K, int ldw)
{
    __shared__ u16 As[128][40];   // +8 pad
    __shared__ u16 Ws[128][40];

    const int m0 = blockIdx.y * 128;
    const int n0 = blockIdx.x * 128;
    const int tid  = threadIdx.x;
    const int lane = tid & 63;
    const int wv   = tid >> 6;
    const int mb   = (wv >> 1) * 64;
    const int nb   = (wv & 1) * 64;
    const int fr   = lane & 15;
    const int q8   = (lane >> 4) * 8;

    const int srow = tid >> 3;
    const int sc4  = (tid & 7) * 4;

    f32x4 acc[4][4];
#pragma unroll
    for (int i = 0; i < 4; i++)
#pragma unroll
        for (int j = 0; j < 4; j++) acc[i][j] = (f32x4){0.f, 0.f, 0.f, 0.f};

    for (int k0 = 0; k0 < K; k0 += 32) {
        __syncthreads();
#pragma unroll
        for (int i = 0; i < 4; i++) {
            int r = srow + i * 32;
            const TA* ap = A + (size_t)(m0 + r) * K + k0 + sc4;
            const float* wp = W + (size_t)(n0 + r) * ldw + k0 + sc4;
            if (k0 + sc4 + 3 < K) {
                As[r][sc4+0] = f2bu(tf(ap[0])); As[r][sc4+1] = f2bu(tf(ap[1]));
                As[r][sc4+2] = f2bu(tf(ap[2])); As[r][sc4+3] = f2bu(tf(ap[3]));
                Ws[r][sc4+0] = f2bu(wp[0]); Ws[r][sc4+1] = f2bu(wp[1]);
                Ws[r][sc4+2] = f2bu(wp[2]); Ws[r][sc4+3] = f2bu(wp[3]);
            } else {
#pragma unroll
                for (int u = 0; u < 4; u++) {
                    int kk = k0 + sc4 + u;
                    As[r][sc4+u] = (kk < K) ? f2bu(tf(ap[u])) : 0;
                    Ws[r][sc4+u] = (kk < K) ? f2bu(wp[u]) : 0;
                }
            }
        }
        __syncthreads();

        short8 af[4], bf[4];
#pragma unroll
        for (int i = 0; i < 4; i++) af[i] = *(const short8*)&As[mb + i*16 + fr][q8];
#pragma unroll
        for (int j = 0; j < 4; j++) bf[j] = *(const short8*)&Ws[nb + j*16 + fr][q8];
#pragma unroll
        for (int i = 0; i < 4; i++)
#pragma unroll
            for (int j = 0; j < 4; j++)
                acc[i][j] = __builtin_amdgcn_mfma_f32_16x16x32_bf16(af[i], bf[j], acc[i][j], 0, 0, 0);
    }

#pragma unroll
    for (int i = 0; i < 4; i++) {
#pragma unroll
        for (int j = 0; j < 4; j++) {
            int gn = n0 + nb + j * 16 + fr;
            float bv = bias ? bias[gn] : 0.f;
#pragma unroll
            for (int r = 0; r < 4; r++) {
                int gm = m0 + mb + i * 16 + (lane >> 4) * 4 + r;
                float v = acc[i][j][r] + bv;
                if (RELU) v = fmaxf(v, 0.f);
                stv(&C[(size_t)gm * N + gn], v);
            }
        }
    }
}

// M = W3b @ W2 (256 x 64); sb[d] = row-sum of W3b. W3: (256,512), W2: (256,64)
__global__ void prep_M(const float* __restrict__ W3, const float* __restrict__ W2,
                       float* __restrict__ Mmat, float* __restrict__ sb)
{
    int d = blockIdx.x, a = threadIdx.x;
    float s = 0.f;
    for (int j = 0; j < 256; j++)
        s += W3[d * 512 + 256 + j] * W2[j * 64 + a];
    Mmat[d * 64 + a] = s;
    if (a == 0) {
        float t = 0.f;
        for (int j = 0; j < 256; j++) t += W3[d * 512 + 256 + j];
        sb[d] = t;
    }
}

// ---------------------------------------------------------------------------
// Per-batch counting sort of edges by column. One block per batch, 512 thr.
// Outputs: deg[j] = in-edge count + 1 (self loop), node_off[j] = batch-local
// exclusive prefix, sorted[b*2048+pos] = batch-local edge index.
// ---------------------------------------------------------------------------
__global__ __launch_bounds__(512)
void sort_edges(const int* __restrict__ ecol, float* __restrict__ deg,
                int* __restrict__ node_off, int* __restrict__ sorted)
{
    const int b = blockIdx.x;
    const int t = threadIdx.x;
    const int base = b * EE;
    __shared__ int cnt[512];
    __shared__ int tmp[512];
    __shared__ int off2[512];

    cnt[t] = 0;
    __syncthreads();
    for (int e = t; e < EE; e += 512) atomicAdd(&cnt[ecol[base + e]], 1);
    __syncthreads();

    int v = cnt[t];
    deg[b * NN + t] = (float)(v + 1);
    tmp[t] = v;
    __syncthreads();
    // Hillis-Steele inclusive scan
    for (int s = 1; s < 512; s <<= 1) {
        int y = (t >= s) ? tmp[t - s] : 0;
        __syncthreads();
        tmp[t] += y;
        __syncthreads();
    }
    int excl = tmp[t] - v;
    node_off[b * NN + t] = excl;
    off2[t] = excl;
    __syncthreads();
    for (int e = t; e < EE; e += 512) {
        int c = ecol[base + e];
        int pos = atomicAdd(&off2[c], 1);
        sorted[base + pos] = e;
    }
}

// ---------------------------------------------------------------------------
// Gather aggregation (no atomics): one block per node, 256 threads.
// agg1[c][d] = sum_e norm_e * y1[row_e][d]   (256 dims)
// eagg[c][a] = sum_e norm_e * ea_e[a]        (64 dims)
// ---------------------------------------------------------------------------
__global__ __launch_bounds__(256)
void edge_gather(const int* __restrict__ erow, const int* __restrict__ sorted,
                 const int* __restrict__ node_off, const float* __restrict__ deg,
                 const float* __restrict__ y1, const float* __restrict__ eattr,
                 float* __restrict__ agg1, float* __restrict__ eagg)
{
    const int j = blockIdx.x;        // global node
    const int b = j >> 9;
    const int c = j & 511;
    const int t = threadIdx.x;
    const int start = node_off[j];
    const int end   = (c == 511) ? EE : node_off[j + 1];
    const float dc = deg[j];

    float acc  = 0.f;
    float acce = 0.f;
    for (int i = start; i < end; i++) {
        int e  = sorted[b * EE + i];
        int eg = b * EE + e;
        int rg = b * NN + erow[eg];
        float norm = rsqrtf(deg[rg] * dc);
        acc += norm * y1[(size_t)rg * 256 + t];
        if (t < 64) acce += norm * eattr[(size_t)eg * 64 + t];
    }
    agg1[(size_t)j * 256 + t] = acc;
    if (t < 64) eagg[(size_t)j * 64 + t] = acce;
}

// h = tanh((agg1 + aggM + (y1+sb)/deg)/deg + bias) * mask -> out (may alias aggM)
__global__ void gcn_finalize(const float* __restrict__ agg1, float* __restrict__ aggM,
                             const float* __restrict__ y1, const float* __restrict__ sb,
                             const float* __restrict__ deg, const float* __restrict__ gcn_bias,
                             const int* __restrict__ lengths)
{
    size_t idx = (size_t)blockIdx.x * 256 + threadIdx.x;
    int j = (int)(idx >> 8);
    int d = (int)(idx & 255);
    float dg = deg[j];
    float a  = (agg1[idx] + aggM[idx] + (y1[idx] + sb[d]) / dg) / dg;
    float h  = tanhf(a + gcn_bias[d]);
    int b = j >> 9, p = j & 511;
    if (p >= lengths[b]) h = 0.f;
    aggM[idx] = h;
}

__global__ void bn_stats(const float* __restrict__ X, float* __restrict__ sums,
                         float* __restrict__ sumsq, int R)
{
    int t = threadIdx.x;
    float s = 0.f, q = 0.f;
    for (int r = blockIdx.x; r < R; r += gridDim.x) {
        float v = X[(size_t)r * DD + t];
        s += v; q += v * v;
    }
    atomicAdd(&sums[t], s);
    atomicAdd(&sumsq[t], q);
}

__global__ void bn_apply(float* __restrict__ X, const float* __restrict__ sums,
                         const float* __restrict__ sumsq, const float* __restrict__ g,
                         const float* __restrict__ bt, int R)
{
    size_t idx = (size_t)blockIdx.x * 256 + threadIdx.x;
    int d = (int)(idx & 255);
    float invR = 1.f / (float)R;
    float m   = sums[d] * invR;
    float var = sumsq[d] * invR - m * m;
    X[idx] = (X[idx] - m) * rsqrtf(fmaxf(var, 0.f) + EPSF) * g[d] + bt[d];
}

// ---------------------------------------------------------------------------
// Attention: one block per (b,h); 512 threads (8 waves).
// K rows in registers; V in LDS transposed bf16; Q-tile (8 rows) f32 in LDS.
// ---------------------------------------------------------------------------
__global__ __launch_bounds__(512)
void attn_kernel(const bf16* __restrict__ qkv, float* __restrict__ out)
{
    const int b = blockIdx.x >> 2;
    const int h = blockIdx.x & 3;
    const int tid = threadIdx.x;
    const int wv  = tid >> 6;
    const int ln  = tid & 63;

    __shared__ u16   Vt[64][516];
    __shared__ float qsf[8][68];
    __shared__ float scf[8][512];
    __shared__ u16   Pb[8][520];
    __shared__ float invs[8];

    const u16* qb = (const u16*)qkv;
    const size_t rowbase = ((size_t)(b * NN + tid)) * 768;

    float kreg[64];
    {
        const uint4* kp = (const uint4*)(qb + rowbase + 256 + h * 64);
#pragma unroll
        for (int c = 0; c < 8; c++) {
            uint4 u = kp[c];
            kreg[c*8+0] = blo(u.x); kreg[c*8+1] = bhi(u.x);
            kreg[c*8+2] = blo(u.y); kreg[c*8+3] = bhi(u.y);
            kreg[c*8+4] = blo(u.z); kreg[c*8+5] = bhi(u.z);
            kreg[c*8+6] = blo(u.w); kreg[c*8+7] = bhi(u.w);
        }
        const uint4* vp = (const uint4*)(qb + rowbase + 512 + h * 64);
#pragma unroll
        for (int c = 0; c < 8; c++) {
            uint4 u = vp[c];
            Vt[c*8+0][tid] = (u16)(u.x & 0xffff); Vt[c*8+1][tid] = (u16)(u.x >> 16);
            Vt[c*8+2][tid] = (u16)(u.y & 0xffff); Vt[c*8+3][tid] = (u16)(u.y >> 16);
            Vt[c*8+4][tid] = (u16)(u.z & 0xffff); Vt[c*8+5][tid] = (u16)(u.z >> 16);
            Vt[c*8+6][tid] = (u16)(u.w & 0xffff); Vt[c*8+7][tid] = (u16)(u.w >> 16);
        }
    }
    __syncthreads();

    const int qq = tid >> 6;
    const int dd = tid & 63;

    for (int t0 = 0; t0 < NN; t0 += 8) {
        {
            unsigned u = qb[((size_t)(b * NN + t0 + qq)) * 768 + h * 64 + dd];
            qsf[qq][dd] = blo(u);
        }
        __syncthreads();

#pragma unroll
        for (int q = 0; q < 8; q++) {
            const float* Qr = qsf[q];
            float s = 0.f;
#pragma unroll
            for (int j = 0; j < 64; j += 4) {
                float4 qv = *(const float4*)(Qr + j);
                s += qv.x * kreg[j] + qv.y * kreg[j+1] + qv.z * kreg[j+2] + qv.w * kreg[j+3];
            }
            scf[q][tid] = s * 0.125f;
        }
        __syncthreads();

        {
            float vv[8];
            float m = -1e30f;
#pragma unroll
            for (int i = 0; i < 8; i++) { vv[i] = scf[wv][ln + 64*i]; m = fmaxf(m, vv[i]); }
#pragma unroll
            for (int off = 32; off > 0; off >>= 1) m = fmaxf(m, __shfl_xor(m, off));
            float ssum = 0.f;
#pragma unroll
            for (int i = 0; i < 8; i++) {
                float e = __expf(vv[i] - m);
                Pb[wv][ln + 64*i] = f2bu(e);
                ssum += e;
            }
#pragma unroll
            for (int off = 32; off > 0; off >>= 1) ssum += __shfl_xor(ssum, off);
            if (ln == 0) invs[wv] = 1.f / ssum;
        }
        __syncthreads();

        {
            const u16* Pr = &Pb[qq][0];
            const u16* Vr = &Vt[dd][0];
            float acc = 0.f;
#pragma unroll 8
            for (int c = 0; c < 64; c++) {
                uint4 pv = *(const uint4*)(Pr + c*8);
                uint2 v0 = *(const uint2*)(Vr + c*8);
                uint2 v1 = *(const uint2*)(Vr + c*8 + 4);
                acc += blo(pv.x) * blo(v0.x) + bhi(pv.x) * bhi(v0.x)
                     + blo(pv.y) * blo(v0.y) + bhi(pv.y) * bhi(v0.y)
                     + blo(pv.z) * blo(v1.x) + bhi(pv.z) * bhi(v1.x)
                     + blo(pv.w) * blo(v1.y) + bhi(pv.w) * bhi(v1.y);
            }
            out[((size_t)(b * NN + t0 + qq)) * 256 + h * 64 + dd] = acc * invs[qq];
        }
        __syncthreads();
    }
}

// out = LN(X + Y); one block per row of 256.
__global__ void add_ln_kernel(const float* __restrict__ X, const float* __restrict__ Y,
                              const float* __restrict__ g, const float* __restrict__ bt,
                              float* __restrict__ out)
{
    int row = blockIdx.x;
    int t   = threadIdx.x;
    size_t idx = (size_t)row * DD + t;
    float v = X[idx] + Y[idx];
    __shared__ float red[DD];
    red[t] = v; __syncthreads();
    for (int s = 128; s > 0; s >>= 1) { if (t < s) red[t] += red[t + s]; __syncthreads(); }
    float m = red[0] * (1.f / DD);
    __syncthreads();
    float d = v - m;
    red[t] = d * d; __syncthreads();
    for (int s = 128; s > 0; s >>= 1) { if (t < s) red[t] += red[t + s]; __syncthreads(); }
    float var = red[0] * (1.f / DD);
    out[idx] = d * rsqrtf(var + EPSF) * g[t] + bt[t];
}

__global__ void pool_kernel(const float* __restrict__ enc, const int* __restrict__ lengths,
                            float* __restrict__ poolbuf)
{
    int b = blockIdx.x;
    int t = threadIdx.x;
    int L = lengths[b];
    if (L < 1) L = 1;
    const float* p = enc + (size_t)b * NN * DD + t;
    float s = 0.f, mx = -1e30f;
    for (int n = 0; n < NN; n++) {
        float v = p[(size_t)n * DD];
        s += v;
        if (n < L) mx = fmaxf(mx, v);
    }
    poolbuf[b * 512 + t]       = mx;
    poolbuf[b * 512 + 256 + t] = s / (float)L;
}

__global__ void head_kernel(const float* __restrict__ poolbuf, const float* __restrict__ lin_w,
                            const float* __restrict__ lin_b, const float* __restrict__ g,
                            const float* __restrict__ bt, float* __restrict__ out)
{
    int b = threadIdx.x;
    float r0 = lin_b[0], r1 = lin_b[1];
    for (int k = 0; k < 512; k++) {
        float p = poolbuf[b * 512 + k];
        r0 += p * lin_w[k];
        r1 += p * lin_w[512 + k];
    }
    __shared__ float s0[64], s1[64], mstat[4];
    s0[b] = r0; s1[b] = r1; __syncthreads();
    if (b == 0) {
        float a0 = 0, a1 = 0, q0 = 0, q1 = 0;
        for (int i = 0; i < 64; i++) { a0 += s0[i]; a1 += s1[i]; }
        a0 *= (1.f / 64.f); a1 *= (1.f / 64.f);
        for (int i = 0; i < 64; i++) {
            float d0 = s0[i] - a0, d1 = s1[i] - a1;
            q0 += d0 * d0; q1 += d1 * d1;
        }
        mstat[0] = a0; mstat[1] = a1; mstat[2] = q0 * (1.f / 64.f); mstat[3] = q1 * (1.f / 64.f);
    }
    __syncthreads();
    float z0 = (r0 - mstat[0]) * rsqrtf(mstat[2] + EPSF) * g[0] + bt[0];
    float z1 = (r1 - mstat[1]) * rsqrtf(mstat[3] + EPSF) * g[1] + bt[1];
    float mx = fmaxf(z0, z1);
    float e0 = __expf(z0 - mx), e1 = __expf(z1 - mx);
    float inv = 1.f / (e0 + e1);
    out[b * 2 + 0] = e0 * inv;
    out[b * 2 + 1] = e1 * inv;
}

extern "C" void kernel_launch(void* const* d_in, const int* in_sizes, int n_in,
                              void* d_out, int out_size, void* d_ws, size_t ws_size,
                              hipStream_t stream)
{
    (void)in_sizes; (void)n_in; (void)out_size; (void)ws_size;
    const float* x          = (const float*)d_in[0];
    const float* edge_attr  = (const float*)d_in[1];
    const float* W1         = (const float*)d_in[5];
    const float* W2         = (const float*)d_in[6];
    const float* W3         = (const float*)d_in[7];
    const float* b3         = (const float*)d_in[8];
    const float* gcn_bias   = (const float*)d_in[9];
    const float* bn1_g      = (const float*)d_in[10];
    const float* bn1_b      = (const float*)d_in[11];
    const float* in_proj_w  = (const float*)d_in[12];
    const float* in_proj_b  = (const float*)d_in[13];
    const float* out_proj_w = (const float*)d_in[14];
    const float* out_proj_b = (const float*)d_in[15];
    const float* ln1_g      = (const float*)d_in[16];
    const float* ln1_b      = (const float*)d_in[17];
    const float* lin1_w     = (const float*)d_in[18];
    const float* lin1_b     = (const float*)d_in[19];
    const float* lin2_w     = (const float*)d_in[20];
    const float* lin2_b     = (const float*)d_in[21];
    const float* ln2_g      = (const float*)d_in[22];
    const float* ln2_b      = (const float*)d_in[23];
    const float* bn2_g      = (const float*)d_in[24];
    const float* bn2_b      = (const float*)d_in[25];
    const float* lin_w      = (const float*)d_in[26];
    const float* lin_b      = (const float*)d_in[27];
    const float* bn3_g      = (const float*)d_in[28];
    const float* bn3_b      = (const float*)d_in[29];

    // ---- Workspace layout: ~171 MB ----
    char* p = (char*)d_ws;
    bf16*  big   = (bf16*)p;  p += (size_t)BN_TOT * 1024 * 2;   // 64 MB: qkv then ffa
    float* bufA  = (float*)p; p += (size_t)BN_TOT * 256 * 4;    // xs -> aggM -> h -> ffb
    float* bufB  = (float*)p; p += (size_t)BN_TOT * 256 * 4;    // y1 -> attnp -> h2
    float* bufC  = (float*)p; p += (size_t)BN_TOT * 256 * 4;    // agg1 -> attnout -> h1
    float* eagg  = (float*)p; p += (size_t)BN_TOT * 64 * 4;     // 8 MB
    float* deg   = (float*)p; p += (size_t)BN_TOT * 4;
    float* Mmat  = (float*)p; p += 256 * 64 * 4;
    float* sb    = (float*)p; p += 1024;
    float* stats = (float*)p; p += 4 * 256 * 4;
    float* poolbuf=(float*)p; p += 64 * 512 * 4;
    int*   flags = (int*)p;   p += 256;
    int*   erc   = (int*)p;   p += BE_TOT * 4;
    int*   ecc   = (int*)p;   p += BE_TOT * 4;
    int*   lenc  = (int*)p;   p += 256;
    int*   sorted= (int*)p;   p += BE_TOT * 4;
    int*   noff  = (int*)p;   p += BN_TOT * 4;

    detect_kernel<<<1, 1, 0, stream>>>((const int*)d_in[4], flags);
    conv_i<<<(BE_TOT + 255) / 256, 256, 0, stream>>>(d_in[2], erc, BE_TOT, flags);
    conv_i<<<(BE_TOT + 255) / 256, 256, 0, stream>>>(d_in[3], ecc, BE_TOT, flags);
    conv_i<<<1, 64, 0, stream>>>(d_in[4], lenc, BB, flags);

    float* xs      = bufA;
    float* y1      = bufB;
    float* agg1    = bufC;
    float* aggM    = bufA;    // xs dead after y1 GEMM; becomes h in finalize
    float* h       = bufA;
    bf16*  qkv     = big;
    float* attnout = bufC;    // agg1 dead after finalize
    float* attnp   = bufB;    // y1 dead after finalize
    float* h1      = bufC;    // attnout dead after out_proj GEMM
    bf16*  ffa     = big;     // qkv dead after attn_kernel
    float* ffb     = bufA;    // h dead after add_ln #1
    float* h2      = bufB;    // attnp dead after add_ln #1

    hipMemsetAsync(stats, 0, 4 * 256 * 4, stream);

    prep_M<<<256, 64, 0, stream>>>(W3, W2, Mmat, sb);
    sort_edges<<<BB, 512, 0, stream>>>(ecc, deg, noff, sorted);

    // xs = x @ W1.T   (K=300 padded)
    gemm_mfma<float, float, 0><<<dim3(256/128, BN_TOT/128), 256, 0, stream>>>(
        x, W1, nullptr, xs, BN_TOT, 256, FINK, FINK);
    // y1 = xs @ W3a.T + b3  (ldw=512)
    gemm_mfma<float, float, 0><<<dim3(256/128, BN_TOT/128), 256, 0, stream>>>(
        xs, W3, b3, y1, BN_TOT, 256, 256, 512);

    // gather (no atomics), then lift eagg 64->256 via M
    edge_gather<<<BN_TOT, 256, 0, stream>>>(erc, sorted, noff, deg, y1, edge_attr, agg1, eagg);
    gemm_mfma<float, float, 0><<<dim3(256/128, BN_TOT/128), 256, 0, stream>>>(
        eagg, Mmat, nullptr, aggM, BN_TOT, 256, 64, 64);

    gcn_finalize<<<BN_TOT, 256, 0, stream>>>(agg1, aggM, y1, sb, deg, gcn_bias, lenc);

    bn_stats<<<512, 256, 0, stream>>>(h, stats, stats + 256, BN_TOT);
    bn_apply<<<BN_TOT, 256, 0, stream>>>(h, stats, stats + 256, bn1_g, bn1_b, BN_TOT);

    gemm_mfma<float, bf16, 0><<<dim3(768/128, BN_TOT/128), 256, 0, stream>>>(
        h, in_proj_w, in_proj_b, qkv, BN_TOT, 768, 256, 256);

    attn_kernel<<<BB * 4, 512, 0, stream>>>(qkv, attnout);

    gemm_mfma<float, float, 0><<<dim3(256/128, BN_TOT/128), 256, 0, stream>>>(
        attnout, out_proj_w, out_proj_b, attnp, BN_TOT, 256, 256, 256);

    add_ln_kernel<<<BN_TOT, 256, 0, stream>>>(h, attnp, ln1_g, ln1_b, h1);

    gemm_mfma<float, bf16, 1><<<dim3(1024/128, BN_TOT/128), 256, 0, stream>>>(
        h1, lin1_w, lin1_b, ffa, BN_TOT, 1024, 256, 256);
    gemm_mfma<bf16, float, 0><<<dim3(256/128, BN_TOT/128), 256, 0, stream>>>(
        ffa, lin2_w, lin2_b, ffb, BN_TOT, 256, 1024, 1024);

    add_ln_kernel<<<BN_TOT, 256, 0, stream>>>(h1, ffb, ln2_g, ln2_b, h2);

    bn_stats<<<512, 256, 0, stream>>>(h2, stats + 512, stats + 768, BN_TOT);
    bn_apply<<<BN_TOT, 256, 0, stream>>>(h2, stats + 512, stats + 768, bn2_g, bn2_b, BN_TOT);

    pool_kernel<<<64, 256, 0, stream>>>(h2, lenc, poolbuf);
    head_kernel<<<1, 64, 0, stream>>>(poolbuf, lin_w, lin_b, bn3_g, bn3_b, (float*)d_out);
}

// Round 8
// 842.592 us; speedup vs baseline: 10.0549x; 1.9326x over previous
//
#include <hip/hip_runtime.h>
#include <hip/hip_bf16.h>

// Shapes
#define BB   64
#define NN   512
#define EE   2048
#define FINK 300
#define DD   256
#define BN_TOT (BB*NN)    // 32768
#define BE_TOT (BB*EE)    // 131072
#define EPSF 1e-5f

using bf16 = __hip_bfloat16;
typedef unsigned short u16;
typedef __attribute__((ext_vector_type(8))) short short8;
typedef __attribute__((ext_vector_type(4))) float f32x4;

__device__ __forceinline__ float tf(float x) { return x; }
__device__ __forceinline__ float tf(bf16 x)  { return __bfloat162float(x); }
__device__ __forceinline__ void  stv(float* p, float v) { *p = v; }
__device__ __forceinline__ void  stv(bf16*  p, float v) { *p = __float2bfloat16(v); }

__device__ __forceinline__ u16 f2bu(float f) {
    bf16 b = __float2bfloat16(f);
    return *(u16*)&b;
}
__device__ __forceinline__ float blo(unsigned u) {
    unsigned x = u << 16; return *(float*)&x;
}

// Int dtype probe: lengths[1] as int32 is in [256,512] iff int32 storage;
// it is the zero hi-word of lengths[0] iff int64 (LE).
__global__ void detect_kernel(const int* __restrict__ lengths, int* __restrict__ flags)
{
    flags[1] = (lengths[1] == 0) ? 1 : 0;
}

__global__ void conv_i(const void* __restrict__ src, int* __restrict__ dst, int n,
                       const int* __restrict__ flags)
{
    int i = blockIdx.x * 256 + threadIdx.x;
    if (i >= n) return;
    const int* s = (const int*)src;
    dst[i] = s[flags[1] ? (i << 1) : i];
}

// ---------------------------------------------------------------------------
// MFMA GEMM: C[m,n] = sum_k A[m,k]*W[n*ldw+k] (+bias,+relu)
// Tile 128x128, 4 waves (2x2 of 64x64), K-step 32, bf16 LDS staging.
// ---------------------------------------------------------------------------
template<typename TA, typename TC, int RELU>
__global__ __launch_bounds__(256)
void gemm_mfma(const TA* __restrict__ A, const float* __restrict__ W,
               const float* __restrict__ bias, TC* __restrict__ C,
               int M, int N, int K, int ldw)
{
    __shared__ u16 As[128][40];   // +8 pad
    __shared__ u16 Ws[128][40];

    const int m0 = blockIdx.y * 128;
    const int n0 = blockIdx.x * 128;
    const int tid  = threadIdx.x;
    const int lane = tid & 63;
    const int wv   = tid >> 6;
    const int mb   = (wv >> 1) * 64;
    const int nb   = (wv & 1) * 64;
    const int fr   = lane & 15;
    const int q8   = (lane >> 4) * 8;

    const int srow = tid >> 3;
    const int sc4  = (tid & 7) * 4;

    f32x4 acc[4][4];
#pragma unroll
    for (int i = 0; i < 4; i++)
#pragma unroll
        for (int j = 0; j < 4; j++) acc[i][j] = (f32x4){0.f, 0.f, 0.f, 0.f};

    for (int k0 = 0; k0 < K; k0 += 32) {
        __syncthreads();
#pragma unroll
        for (int i = 0; i < 4; i++) {
            int r = srow + i * 32;
            const TA* ap = A + (size_t)(m0 + r) * K + k0 + sc4;
            const float* wp = W + (size_t)(n0 + r) * ldw + k0 + sc4;
            if (k0 + sc4 + 3 < K) {
                As[r][sc4+0] = f2bu(tf(ap[0])); As[r][sc4+1] = f2bu(tf(ap[1]));
                As[r][sc4+2] = f2bu(tf(ap[2])); As[r][sc4+3] = f2bu(tf(ap[3]));
                Ws[r][sc4+0] = f2bu(wp[0]); Ws[r][sc4+1] = f2bu(wp[1]);
                Ws[r][sc4+2] = f2bu(wp[2]); Ws[r][sc4+3] = f2bu(wp[3]);
            } else {
#pragma unroll
                for (int u = 0; u < 4; u++) {
                    int kk = k0 + sc4 + u;
                    As[r][sc4+u] = (kk < K) ? f2bu(tf(ap[u])) : 0;
                    Ws[r][sc4+u] = (kk < K) ? f2bu(wp[u]) : 0;
                }
            }
        }
        __syncthreads();

        short8 af[4], bf[4];
#pragma unroll
        for (int i = 0; i < 4; i++) af[i] = *(const short8*)&As[mb + i*16 + fr][q8];
#pragma unroll
        for (int j = 0; j < 4; j++) bf[j] = *(const short8*)&Ws[nb + j*16 + fr][q8];
#pragma unroll
        for (int i = 0; i < 4; i++)
#pragma unroll
            for (int j = 0; j < 4; j++)
                acc[i][j] = __builtin_amdgcn_mfma_f32_16x16x32_bf16(af[i], bf[j], acc[i][j], 0, 0, 0);
    }

#pragma unroll
    for (int i = 0; i < 4; i++) {
#pragma unroll
        for (int j = 0; j < 4; j++) {
            int gn = n0 + nb + j * 16 + fr;
            float bv = bias ? bias[gn] : 0.f;
#pragma unroll
            for (int r = 0; r < 4; r++) {
                int gm = m0 + mb + i * 16 + (lane >> 4) * 4 + r;
                float v = acc[i][j][r] + bv;
                if (RELU) v = fmaxf(v, 0.f);
                stv(&C[(size_t)gm * N + gn], v);
            }
        }
    }
}

// M = W3b @ W2 (256 x 64); sb[d] = row-sum of W3b. W3: (256,512), W2: (256,64)
__global__ void prep_M(const float* __restrict__ W3, const float* __restrict__ W2,
                       float* __restrict__ Mmat, float* __restrict__ sb)
{
    int d = blockIdx.x, a = threadIdx.x;
    float s = 0.f;
    for (int j = 0; j < 256; j++)
        s += W3[d * 512 + 256 + j] * W2[j * 64 + a];
    Mmat[d * 64 + a] = s;
    if (a == 0) {
        float t = 0.f;
        for (int j = 0; j < 256; j++) t += W3[d * 512 + 256 + j];
        sb[d] = t;
    }
}

// ---------------------------------------------------------------------------
// Per-batch counting sort of edges by column. One block per batch, 512 thr.
// ---------------------------------------------------------------------------
__global__ __launch_bounds__(512)
void sort_edges(const int* __restrict__ ecol, float* __restrict__ deg,
                int* __restrict__ node_off, int* __restrict__ sorted)
{
    const int b = blockIdx.x;
    const int t = threadIdx.x;
    const int base = b * EE;
    __shared__ int cnt[512];
    __shared__ int tmp[512];
    __shared__ int off2[512];

    cnt[t] = 0;
    __syncthreads();
    for (int e = t; e < EE; e += 512) atomicAdd(&cnt[ecol[base + e]], 1);
    __syncthreads();

    int v = cnt[t];
    deg[b * NN + t] = (float)(v + 1);
    tmp[t] = v;
    __syncthreads();
    for (int s = 1; s < 512; s <<= 1) {
        int y = (t >= s) ? tmp[t - s] : 0;
        __syncthreads();
        tmp[t] += y;
        __syncthreads();
    }
    int excl = tmp[t] - v;
    node_off[b * NN + t] = excl;
    off2[t] = excl;
    __syncthreads();
    for (int e = t; e < EE; e += 512) {
        int c = ecol[base + e];
        int pos = atomicAdd(&off2[c], 1);
        sorted[base + pos] = e;
    }
}

// ---------------------------------------------------------------------------
// Gather aggregation (no atomics): one block per node, 256 threads.
// ---------------------------------------------------------------------------
__global__ __launch_bounds__(256)
void edge_gather(const int* __restrict__ erow, const int* __restrict__ sorted,
                 const int* __restrict__ node_off, const float* __restrict__ deg,
                 const float* __restrict__ y1, const float* __restrict__ eattr,
                 float* __restrict__ agg1, float* __restrict__ eagg)
{
    const int j = blockIdx.x;
    const int b = j >> 9;
    const int c = j & 511;
    const int t = threadIdx.x;
    const int start = node_off[j];
    const int end   = (c == 511) ? EE : node_off[j + 1];
    const float dc = deg[j];

    float acc  = 0.f;
    float acce = 0.f;
    for (int i = start; i < end; i++) {
        int e  = sorted[b * EE + i];
        int eg = b * EE + e;
        int rg = b * NN + erow[eg];
        float norm = rsqrtf(deg[rg] * dc);
        acc += norm * y1[(size_t)rg * 256 + t];
        if (t < 64) acce += norm * eattr[(size_t)eg * 64 + t];
    }
    agg1[(size_t)j * 256 + t] = acc;
    if (t < 64) eagg[(size_t)j * 64 + t] = acce;
}

// h = tanh((agg1 + aggM + (y1+sb)/deg)/deg + bias) * mask -> aggM in place
__global__ void gcn_finalize(const float* __restrict__ agg1, float* __restrict__ aggM,
                             const float* __restrict__ y1, const float* __restrict__ sb,
                             const float* __restrict__ deg, const float* __restrict__ gcn_bias,
                             const int* __restrict__ lengths)
{
    size_t idx = (size_t)blockIdx.x * 256 + threadIdx.x;
    int j = (int)(idx >> 8);
    int d = (int)(idx & 255);
    float dg = deg[j];
    float a  = (agg1[idx] + aggM[idx] + (y1[idx] + sb[d]) / dg) / dg;
    float h  = tanhf(a + gcn_bias[d]);
    int b = j >> 9, p = j & 511;
    if (p >= lengths[b]) h = 0.f;
    aggM[idx] = h;
}

__global__ void bn_stats(const float* __restrict__ X, float* __restrict__ sums,
                         float* __restrict__ sumsq, int R)
{
    int t = threadIdx.x;
    float s = 0.f, q = 0.f;
    for (int r = blockIdx.x; r < R; r += gridDim.x) {
        float v = X[(size_t)r * DD + t];
        s += v; q += v * v;
    }
    atomicAdd(&sums[t], s);
    atomicAdd(&sumsq[t], q);
}

__global__ void bn_apply(float* __restrict__ X, const float* __restrict__ sums,
                         const float* __restrict__ sumsq, const float* __restrict__ g,
                         const float* __restrict__ bt, int R)
{
    size_t idx = (size_t)blockIdx.x * 256 + threadIdx.x;
    int d = (int)(idx & 255);
    float invR = 1.f / (float)R;
    float m   = sums[d] * invR;
    float var = sumsq[d] * invR - m * m;
    X[idx] = (X[idx] - m) * rsqrtf(fmaxf(var, 0.f) + EPSF) * g[d] + bt[d];
}

// ---------------------------------------------------------------------------
// MFMA flash attention. One block per (b, h, 64-row q-tile): 2048 blocks,
// 256 threads (4 waves; wave wv owns q-rows [wv*16, wv*16+16)).
// Per 128-key chunk: S-band via MFMA (C layout row=quad*4+reg matches the
// per-lane online-softmax state), P->LDS bf16 (wave-private band, no barrier),
// PV via MFMA into O accumulators; final O /= l.
// LDS 62.5 KB -> 2 blocks/CU.
// ---------------------------------------------------------------------------
__global__ __launch_bounds__(256)
void attn_mfma(const bf16* __restrict__ qkv, float* __restrict__ out)
{
    const int bid = blockIdx.x;
    const int qt = bid & 7;
    const int h  = (bid >> 3) & 3;
    const int b  = bid >> 5;

    const int tid  = threadIdx.x;
    const int lane = tid & 63;
    const int wv   = tid >> 6;
    const int fr   = lane & 15;
    const int quad = lane >> 4;
    const int q8   = quad * 8;

    __shared__ u16 Qs[64][72];     // q-tile (64 x 64)
    __shared__ u16 Ks[128][72];    // key chunk (128 x 64)
    __shared__ u16 Vts[64][136];   // V^T chunk (64 d x 128 k)
    __shared__ u16 Ps[64][136];    // P (64 q x 128 k)

    const u16* qb = (const u16*)qkv;
    const size_t bb = (size_t)(b * NN);

    // stage Q tile
#pragma unroll
    for (int i = 0; i < 2; i++) {
        int idx = i * 256 + tid;             // 0..511
        int r = idx >> 3, seg = idx & 7;
        uint4 u = *((const uint4*)(qb + (bb + qt * 64 + r) * 768 + h * 64) + seg);
        *(uint4*)&Qs[r][seg * 8] = u;
    }

    f32x4 O[4];
#pragma unroll
    for (int t = 0; t < 4; t++) O[t] = (f32x4){0.f, 0.f, 0.f, 0.f};
    float m_i[4] = {-1e30f, -1e30f, -1e30f, -1e30f};
    float l_i[4] = {0.f, 0.f, 0.f, 0.f};

    for (int c = 0; c < 4; c++) {
        __syncthreads();
        // stage K chunk + V^T chunk
#pragma unroll
        for (int i = 0; i < 4; i++) {
            int idx = i * 256 + tid;         // 0..1023
            int r = idx >> 3, seg = idx & 7;
            uint4 u = *((const uint4*)(qb + (bb + c * 128 + r) * 768 + 256 + h * 64) + seg);
            *(uint4*)&Ks[r][seg * 8] = u;
            uint4 v = *((const uint4*)(qb + (bb + c * 128 + r) * 768 + 512 + h * 64) + seg);
            u16* dst = &Vts[seg * 8][r];
            dst[0*136] = (u16)(v.x & 0xffff); dst[1*136] = (u16)(v.x >> 16);
            dst[2*136] = (u16)(v.y & 0xffff); dst[3*136] = (u16)(v.y >> 16);
            dst[4*136] = (u16)(v.z & 0xffff); dst[5*136] = (u16)(v.z >> 16);
            dst[6*136] = (u16)(v.w & 0xffff); dst[7*136] = (u16)(v.w >> 16);
        }
        __syncthreads();

        // S band = Q(16x64) @ K_chunk^T  -> 8 col-tiles
        f32x4 S[8];
#pragma unroll
        for (int t = 0; t < 8; t++) S[t] = (f32x4){0.f, 0.f, 0.f, 0.f};
#pragma unroll
        for (int ks = 0; ks < 2; ks++) {
            short8 aq = *(const short8*)&Qs[wv * 16 + fr][ks * 32 + q8];
#pragma unroll
            for (int t = 0; t < 8; t++) {
                short8 bk = *(const short8*)&Ks[t * 16 + fr][ks * 32 + q8];
                S[t] = __builtin_amdgcn_mfma_f32_16x16x32_bf16(aq, bk, S[t], 0, 0, 0);
            }
        }

        // online softmax (rows quad*4+r, cols t*16+fr)
        float mc[4];
#pragma unroll
        for (int r = 0; r < 4; r++) {
            float mm = -1e30f;
#pragma unroll
            for (int t = 0; t < 8; t++) { S[t][r] *= 0.125f; mm = fmaxf(mm, S[t][r]); }
            mc[r] = mm;
        }
#pragma unroll
        for (int msk = 1; msk < 16; msk <<= 1)
#pragma unroll
            for (int r = 0; r < 4; r++) mc[r] = fmaxf(mc[r], __shfl_xor(mc[r], msk));

        float alpha[4], ls[4];
#pragma unroll
        for (int r = 0; r < 4; r++) {
            float mn = fmaxf(m_i[r], mc[r]);
            alpha[r] = __expf(m_i[r] - mn);
            m_i[r] = mn;
            ls[r] = 0.f;
        }
#pragma unroll
        for (int t = 0; t < 8; t++)
#pragma unroll
            for (int r = 0; r < 4; r++) {
                float p = __expf(S[t][r] - m_i[r]);
                Ps[wv * 16 + quad * 4 + r][t * 16 + fr] = f2bu(p);
                ls[r] += p;
            }
#pragma unroll
        for (int msk = 1; msk < 16; msk <<= 1)
#pragma unroll
            for (int r = 0; r < 4; r++) ls[r] += __shfl_xor(ls[r], msk);
#pragma unroll
        for (int r = 0; r < 4; r++) l_i[r] = l_i[r] * alpha[r] + ls[r];
#pragma unroll
        for (int t = 0; t < 4; t++)
#pragma unroll
            for (int r = 0; r < 4; r++) O[t][r] *= alpha[r];

        // O band += P(16x128) @ V_chunk(128x64)
#pragma unroll
        for (int ks = 0; ks < 4; ks++) {
            short8 ap = *(const short8*)&Ps[wv * 16 + fr][ks * 32 + q8];
#pragma unroll
            for (int t = 0; t < 4; t++) {
                short8 bv = *(const short8*)&Vts[t * 16 + fr][ks * 32 + q8];
                O[t] = __builtin_amdgcn_mfma_f32_16x16x32_bf16(ap, bv, O[t], 0, 0, 0);
            }
        }
    }

    // write O / l  (row = qt*64 + wv*16 + quad*4 + r, col = h*64 + t*16 + fr)
#pragma unroll
    for (int t = 0; t < 4; t++)
#pragma unroll
        for (int r = 0; r < 4; r++) {
            int q = qt * 64 + wv * 16 + quad * 4 + r;
            out[(bb + q) * 256 + h * 64 + t * 16 + fr] = O[t][r] / l_i[r];
        }
}

// out = LN(X + Y); one block per row of 256.
__global__ void add_ln_kernel(const float* __restrict__ X, const float* __restrict__ Y,
                              const float* __restrict__ g, const float* __restrict__ bt,
                              float* __restrict__ out)
{
    int row = blockIdx.x;
    int t   = threadIdx.x;
    size_t idx = (size_t)row * DD + t;
    float v = X[idx] + Y[idx];
    __shared__ float red[DD];
    red[t] = v; __syncthreads();
    for (int s = 128; s > 0; s >>= 1) { if (t < s) red[t] += red[t + s]; __syncthreads(); }
    float m = red[0] * (1.f / DD);
    __syncthreads();
    float d = v - m;
    red[t] = d * d; __syncthreads();
    for (int s = 128; s > 0; s >>= 1) { if (t < s) red[t] += red[t + s]; __syncthreads(); }
    float var = red[0] * (1.f / DD);
    out[idx] = d * rsqrtf(var + EPSF) * g[t] + bt[t];
}

__global__ void pool_kernel(const float* __restrict__ enc, const int* __restrict__ lengths,
                            float* __restrict__ poolbuf)
{
    int b = blockIdx.x;
    int t = threadIdx.x;
    int L = lengths[b];
    if (L < 1) L = 1;
    const float* p = enc + (size_t)b * NN * DD + t;
    float s = 0.f, mx = -1e30f;
    for (int n = 0; n < NN; n++) {
        float v = p[(size_t)n * DD];
        s += v;
        if (n < L) mx = fmaxf(mx, v);
    }
    poolbuf[b * 512 + t]       = mx;
    poolbuf[b * 512 + 256 + t] = s / (float)L;
}

__global__ void head_kernel(const float* __restrict__ poolbuf, const float* __restrict__ lin_w,
                            const float* __restrict__ lin_b, const float* __restrict__ g,
                            const float* __restrict__ bt, float* __restrict__ out)
{
    int b = threadIdx.x;
    float r0 = lin_b[0], r1 = lin_b[1];
    for (int k = 0; k < 512; k++) {
        float p = poolbuf[b * 512 + k];
        r0 += p * lin_w[k];
        r1 += p * lin_w[512 + k];
    }
    __shared__ float s0[64], s1[64], mstat[4];
    s0[b] = r0; s1[b] = r1; __syncthreads();
    if (b == 0) {
        float a0 = 0, a1 = 0, q0 = 0, q1 = 0;
        for (int i = 0; i < 64; i++) { a0 += s0[i]; a1 += s1[i]; }
        a0 *= (1.f / 64.f); a1 *= (1.f / 64.f);
        for (int i = 0; i < 64; i++) {
            float d0 = s0[i] - a0, d1 = s1[i] - a1;
            q0 += d0 * d0; q1 += d1 * d1;
        }
        mstat[0] = a0; mstat[1] = a1; mstat[2] = q0 * (1.f / 64.f); mstat[3] = q1 * (1.f / 64.f);
    }
    __syncthreads();
    float z0 = (r0 - mstat[0]) * rsqrtf(mstat[2] + EPSF) * g[0] + bt[0];
    float z1 = (r1 - mstat[1]) * rsqrtf(mstat[3] + EPSF) * g[1] + bt[1];
    float mx = fmaxf(z0, z1);
    float e0 = __expf(z0 - mx), e1 = __expf(z1 - mx);
    float inv = 1.f / (e0 + e1);
    out[b * 2 + 0] = e0 * inv;
    out[b * 2 + 1] = e1 * inv;
}

extern "C" void kernel_launch(void* const* d_in, const int* in_sizes, int n_in,
                              void* d_out, int out_size, void* d_ws, size_t ws_size,
                              hipStream_t stream)
{
    (void)in_sizes; (void)n_in; (void)out_size; (void)ws_size;
    const float* x          = (const float*)d_in[0];
    const float* edge_attr  = (const float*)d_in[1];
    const float* W1         = (const float*)d_in[5];
    const float* W2         = (const float*)d_in[6];
    const float* W3         = (const float*)d_in[7];
    const float* b3         = (const float*)d_in[8];
    const float* gcn_bias   = (const float*)d_in[9];
    const float* bn1_g      = (const float*)d_in[10];
    const float* bn1_b      = (const float*)d_in[11];
    const float* in_proj_w  = (const float*)d_in[12];
    const float* in_proj_b  = (const float*)d_in[13];
    const float* out_proj_w = (const float*)d_in[14];
    const float* out_proj_b = (const float*)d_in[15];
    const float* ln1_g      = (const float*)d_in[16];
    const float* ln1_b      = (const float*)d_in[17];
    const float* lin1_w     = (const float*)d_in[18];
    const float* lin1_b     = (const float*)d_in[19];
    const float* lin2_w     = (const float*)d_in[20];
    const float* lin2_b     = (const float*)d_in[21];
    const float* ln2_g      = (const float*)d_in[22];
    const float* ln2_b      = (const float*)d_in[23];
    const float* bn2_g      = (const float*)d_in[24];
    const float* bn2_b      = (const float*)d_in[25];
    const float* lin_w      = (const float*)d_in[26];
    const float* lin_b      = (const float*)d_in[27];
    const float* bn3_g      = (const float*)d_in[28];
    const float* bn3_b      = (const float*)d_in[29];

    // ---- Workspace layout: ~171 MB ----
    char* p = (char*)d_ws;
    bf16*  big   = (bf16*)p;  p += (size_t)BN_TOT * 1024 * 2;   // 64 MB: qkv then ffa
    float* bufA  = (float*)p; p += (size_t)BN_TOT * 256 * 4;    // xs -> aggM -> h -> ffb
    float* bufB  = (float*)p; p += (size_t)BN_TOT * 256 * 4;    // y1 -> attnp -> h2
    float* bufC  = (float*)p; p += (size_t)BN_TOT * 256 * 4;    // agg1 -> attnout -> h1
    float* eagg  = (float*)p; p += (size_t)BN_TOT * 64 * 4;     // 8 MB
    float* deg   = (float*)p; p += (size_t)BN_TOT * 4;
    float* Mmat  = (float*)p; p += 256 * 64 * 4;
    float* sb    = (float*)p; p += 1024;
    float* stats = (float*)p; p += 4 * 256 * 4;
    float* poolbuf=(float*)p; p += 64 * 512 * 4;
    int*   flags = (int*)p;   p += 256;
    int*   erc   = (int*)p;   p += BE_TOT * 4;
    int*   ecc   = (int*)p;   p += BE_TOT * 4;
    int*   lenc  = (int*)p;   p += 256;
    int*   sorted= (int*)p;   p += BE_TOT * 4;
    int*   noff  = (int*)p;   p += BN_TOT * 4;

    detect_kernel<<<1, 1, 0, stream>>>((const int*)d_in[4], flags);
    conv_i<<<(BE_TOT + 255) / 256, 256, 0, stream>>>(d_in[2], erc, BE_TOT, flags);
    conv_i<<<(BE_TOT + 255) / 256, 256, 0, stream>>>(d_in[3], ecc, BE_TOT, flags);
    conv_i<<<1, 64, 0, stream>>>(d_in[4], lenc, BB, flags);

    float* xs      = bufA;
    float* y1      = bufB;
    float* agg1    = bufC;
    float* aggM    = bufA;    // xs dead after y1 GEMM; becomes h in finalize
    float* h       = bufA;
    bf16*  qkv     = big;
    float* attnout = bufC;    // agg1 dead after finalize
    float* attnp   = bufB;    // y1 dead after finalize
    float* h1      = bufC;    // attnout dead after out_proj GEMM
    bf16*  ffa     = big;     // qkv dead after attn
    float* ffb     = bufA;    // h dead after add_ln #1
    float* h2      = bufB;    // attnp dead after add_ln #1

    hipMemsetAsync(stats, 0, 4 * 256 * 4, stream);

    prep_M<<<256, 64, 0, stream>>>(W3, W2, Mmat, sb);
    sort_edges<<<BB, 512, 0, stream>>>(ecc, deg, noff, sorted);

    gemm_mfma<float, float, 0><<<dim3(256/128, BN_TOT/128), 256, 0, stream>>>(
        x, W1, nullptr, xs, BN_TOT, 256, FINK, FINK);
    gemm_mfma<float, float, 0><<<dim3(256/128, BN_TOT/128), 256, 0, stream>>>(
        xs, W3, b3, y1, BN_TOT, 256, 256, 512);

    edge_gather<<<BN_TOT, 256, 0, stream>>>(erc, sorted, noff, deg, y1, edge_attr, agg1, eagg);
    gemm_mfma<float, float, 0><<<dim3(256/128, BN_TOT/128), 256, 0, stream>>>(
        eagg, Mmat, nullptr, aggM, BN_TOT, 256, 64, 64);

    gcn_finalize<<<BN_TOT, 256, 0, stream>>>(agg1, aggM, y1, sb, deg, gcn_bias, lenc);

    bn_stats<<<512, 256, 0, stream>>>(h, stats, stats + 256, BN_TOT);
    bn_apply<<<BN_TOT, 256, 0, stream>>>(h, stats, stats + 256, bn1_g, bn1_b, BN_TOT);

    gemm_mfma<float, bf16, 0><<<dim3(768/128, BN_TOT/128), 256, 0, stream>>>(
        h, in_proj_w, in_proj_b, qkv, BN_TOT, 768, 256, 256);

    attn_mfma<<<BB * 4 * 8, 256, 0, stream>>>(qkv, attnout);

    gemm_mfma<float, float, 0><<<dim3(256/128, BN_TOT/128), 256, 0, stream>>>(
        attnout, out_proj_w, out_proj_b, attnp, BN_TOT, 256, 256, 256);

    add_ln_kernel<<<BN_TOT, 256, 0, stream>>>(h, attnp, ln1_g, ln1_b, h1);

    gemm_mfma<float, bf16, 1><<<dim3(1024/128, BN_TOT/128), 256, 0, stream>>>(
        h1, lin1_w, lin1_b, ffa, BN_TOT, 1024, 256, 256);
    gemm_mfma<bf16, float, 0><<<dim3(256/128, BN_TOT/128), 256, 0, stream>>>(
        ffa, lin2_w, lin2_b, ffb, BN_TOT, 256, 1024, 1024);

    add_ln_kernel<<<BN_TOT, 256, 0, stream>>>(h1, ffb, ln2_g, ln2_b, h2);

    bn_stats<<<512, 256, 0, stream>>>(h2, stats + 512, stats + 768, BN_TOT);
    bn_apply<<<BN_TOT, 256, 0, stream>>>(h2, stats + 512, stats + 768, bn2_g, bn2_b, BN_TOT);

    pool_kernel<<<64, 256, 0, stream>>>(h2, lenc, poolbuf);
    head_kernel<<<1, 64, 0, stream>>>(poolbuf, lin_w, lin_b, bn3_g, bn3_b, (float*)d_out);
}

// Round 9
// 736.866 us; speedup vs baseline: 11.4976x; 1.1435x over previous
//
#include <hip/hip_runtime.h>
#include <hip/hip_bf16.h>

// Shapes
#define BB   64
#define NN   512
#define EE   2048
#define FINK 300
#define DD   256
#define BN_TOT (BB*NN)    // 32768
#define BE_TOT (BB*EE)    // 131072
#define EPSF 1e-5f

using bf16 = __hip_bfloat16;
typedef unsigned short u16;
typedef __attribute__((ext_vector_type(8))) short short8;
typedef __attribute__((ext_vector_type(4))) float f32x4;

__device__ __forceinline__ float tf(float x) { return x; }
__device__ __forceinline__ float tf(bf16 x)  { return __bfloat162float(x); }
__device__ __forceinline__ void  stv(float* p, float v) { *p = v; }
__device__ __forceinline__ void  stv(bf16*  p, float v) { *p = __float2bfloat16(v); }

__device__ __forceinline__ u16 f2bu(float f) {
    bf16 b = __float2bfloat16(f);
    return *(u16*)&b;
}
__device__ __forceinline__ float blo(unsigned u) {
    unsigned x = u << 16; return *(float*)&x;
}

// Direct global->LDS DMA, 16B per lane. LDS dst = wave-uniform base + lane*16.
__device__ __forceinline__ void gload16(const void* g, void* l)
{
    __builtin_amdgcn_global_load_lds((const __attribute__((address_space(1))) void*)g,
                                     (__attribute__((address_space(3))) void*)l, 16, 0, 0);
}

// Int dtype probe: lengths[1] as int32 is in [256,512] iff int32 storage;
// it is the zero hi-word of lengths[0] iff int64 (LE).
__global__ void detect_kernel(const int* __restrict__ lengths, int* __restrict__ flags)
{
    flags[1] = (lengths[1] == 0) ? 1 : 0;
}

__global__ void conv_i(const void* __restrict__ src, int* __restrict__ dst, int n,
                       const int* __restrict__ flags)
{
    int i = blockIdx.x * 256 + threadIdx.x;
    if (i >= n) return;
    const int* s = (const int*)src;
    dst[i] = s[flags[1] ? (i << 1) : i];
}

// f32 -> bf16 flat
__global__ void conv_f2b(const float* __restrict__ src, u16* __restrict__ dst, int n)
{
    int i = blockIdx.x * 256 + threadIdx.x;
    if (i < n) dst[i] = f2bu(src[i]);
}

// f32 (rows x sk) -> bf16 (rows x dk) zero-padded
__global__ void conv_pad(const float* __restrict__ src, u16* __restrict__ dst, int rows,
                         int sk, int dk)
{
    int i = blockIdx.x * 256 + threadIdx.x;
    if (i >= rows * dk) return;
    int r = i / dk, c = i - r * dk;
    dst[i] = (c < sk) ? f2bu(src[r * sk + c]) : 0;
}

// W3[:, :256] (stride 512) -> bf16 256x256
__global__ void conv_w3a(const float* __restrict__ W3, u16* __restrict__ dst)
{
    int i = blockIdx.x * 256 + threadIdx.x;   // 65536 total
    int r = i >> 8, c = i & 255;
    dst[i] = f2bu(W3[r * 512 + c]);
}

// ---------------------------------------------------------------------------
// m97-style MFMA GEMM: C[m,n] = sum_k A[m,k]*W[n*ldw+k] (+bias,+relu)
// A, W bf16 (u16) row-major; tile 128x128, 4 waves, K-step 32.
// Staging via global_load_lds width=16 into unpadded [128][32] LDS tiles
// (DMA writes lane i at base + i*16B -> rows packed 4 lanes/row).
// M,N multiples of 128; K multiple of 32; lda/ldw elems, rows 16B-aligned.
// ---------------------------------------------------------------------------
template<typename TC, int RELU>
__global__ __launch_bounds__(256)
void gemm_bf(const u16* __restrict__ A, const u16* __restrict__ W,
             const float* __restrict__ bias, TC* __restrict__ C,
             int M, int N, int K, int lda, int ldw)
{
    __shared__ u16 As[128 * 32];
    __shared__ u16 Ws[128 * 32];

    const int m0 = blockIdx.y * 128;
    const int n0 = blockIdx.x * 128;
    const int tid  = threadIdx.x;
    const int lane = tid & 63;
    const int wv   = tid >> 6;
    const int fr   = lane & 15;
    const int q8   = (lane >> 4) * 8;
    const int mb   = (wv >> 1) * 64;
    const int nb   = (wv & 1) * 64;

    const int r16 = lane >> 2;          // 0..15 (staging row within 16-row group)
    const int c8  = (lane & 3) * 8;     // 0,8,16,24 (k sub-offset)

    f32x4 acc[4][4];
#pragma unroll
    for (int i = 0; i < 4; i++)
#pragma unroll
        for (int j = 0; j < 4; j++) acc[i][j] = (f32x4){0.f, 0.f, 0.f, 0.f};

    for (int k0 = 0; k0 < K; k0 += 32) {
        __syncthreads();
#pragma unroll
        for (int j = 0; j < 2; j++) {
            int rowA = m0 + wv * 32 + j * 16 + r16;
            int rowW = n0 + wv * 32 + j * 16 + r16;
            gload16(A + (size_t)rowA * lda + k0 + c8, &As[(wv * 32 + j * 16) * 32]);
            gload16(W + (size_t)rowW * ldw + k0 + c8, &Ws[(wv * 32 + j * 16) * 32]);
        }
        __syncthreads();

        short8 af[4], bf[4];
#pragma unroll
        for (int i = 0; i < 4; i++) af[i] = *(const short8*)&As[(mb + i * 16 + fr) * 32 + q8];
#pragma unroll
        for (int j = 0; j < 4; j++) bf[j] = *(const short8*)&Ws[(nb + j * 16 + fr) * 32 + q8];
#pragma unroll
        for (int i = 0; i < 4; i++)
#pragma unroll
            for (int j = 0; j < 4; j++)
                acc[i][j] = __builtin_amdgcn_mfma_f32_16x16x32_bf16(af[i], bf[j], acc[i][j], 0, 0, 0);
    }

#pragma unroll
    for (int i = 0; i < 4; i++) {
#pragma unroll
        for (int j = 0; j < 4; j++) {
            int gn = n0 + nb + j * 16 + fr;
            float bv = bias ? bias[gn] : 0.f;
#pragma unroll
            for (int r = 0; r < 4; r++) {
                int gm = m0 + mb + i * 16 + (lane >> 4) * 4 + r;
                float v = acc[i][j][r] + bv;
                if (RELU) v = fmaxf(v, 0.f);
                stv(&C[(size_t)gm * N + gn], v);
            }
        }
    }
}

// M = W3b @ W2 (256 x 64) f32+bf16; sb[d] = row-sum of W3b.
__global__ void prep_M(const float* __restrict__ W3, const float* __restrict__ W2,
                       u16* __restrict__ Mb, float* __restrict__ sb)
{
    int d = blockIdx.x, a = threadIdx.x;
    float s = 0.f;
    for (int j = 0; j < 256; j++)
        s += W3[d * 512 + 256 + j] * W2[j * 64 + a];
    Mb[d * 64 + a] = f2bu(s);
    if (a == 0) {
        float t = 0.f;
        for (int j = 0; j < 256; j++) t += W3[d * 512 + 256 + j];
        sb[d] = t;
    }
}

// ---------------------------------------------------------------------------
// Per-batch counting sort of edges by column. One block per batch, 512 thr.
// ---------------------------------------------------------------------------
__global__ __launch_bounds__(512)
void sort_edges(const int* __restrict__ ecol, float* __restrict__ deg,
                int* __restrict__ node_off, int* __restrict__ sorted)
{
    const int b = blockIdx.x;
    const int t = threadIdx.x;
    const int base = b * EE;
    __shared__ int cnt[512];
    __shared__ int tmp[512];
    __shared__ int off2[512];

    cnt[t] = 0;
    __syncthreads();
    for (int e = t; e < EE; e += 512) atomicAdd(&cnt[ecol[base + e]], 1);
    __syncthreads();

    int v = cnt[t];
    deg[b * NN + t] = (float)(v + 1);
    tmp[t] = v;
    __syncthreads();
    for (int s = 1; s < 512; s <<= 1) {
        int y = (t >= s) ? tmp[t - s] : 0;
        __syncthreads();
        tmp[t] += y;
        __syncthreads();
    }
    int excl = tmp[t] - v;
    node_off[b * NN + t] = excl;
    off2[t] = excl;
    __syncthreads();
    for (int e = t; e < EE; e += 512) {
        int c = ecol[base + e];
        int pos = atomicAdd(&off2[c], 1);
        sorted[base + pos] = e;
    }
}

// ---------------------------------------------------------------------------
// Gather aggregation (no atomics): one block per node, 256 threads.
// agg1 f32 (consumed by finalize); eagg written bf16 (GEMM input — the GEMM
// rounds to bf16 at staging anyway, so this is numerically identical).
// ---------------------------------------------------------------------------
__global__ __launch_bounds__(256)
void edge_gather(const int* __restrict__ erow, const int* __restrict__ sorted,
                 const int* __restrict__ node_off, const float* __restrict__ deg,
                 const float* __restrict__ y1, const float* __restrict__ eattr,
                 float* __restrict__ agg1, u16* __restrict__ eaggb)
{
    const int j = blockIdx.x;
    const int b = j >> 9;
    const int c = j & 511;
    const int t = threadIdx.x;
    const int start = node_off[j];
    const int end   = (c == 511) ? EE : node_off[j + 1];
    const float dc = deg[j];

    float acc  = 0.f;
    float acce = 0.f;
    for (int i = start; i < end; i++) {
        int e  = sorted[b * EE + i];
        int eg = b * EE + e;
        int rg = b * NN + erow[eg];
        float norm = rsqrtf(deg[rg] * dc);
        acc += norm * y1[(size_t)rg * 256 + t];
        if (t < 64) acce += norm * eattr[(size_t)eg * 64 + t];
    }
    agg1[(size_t)j * 256 + t] = acc;
    if (t < 64) eaggb[(size_t)j * 64 + t] = f2bu(acce);
}

// h = tanh((agg1 + aggM + (y1+sb)/deg)/deg + bias) * mask -> aggM in place
__global__ void gcn_finalize(const float* __restrict__ agg1, float* __restrict__ aggM,
                             const float* __restrict__ y1, const float* __restrict__ sb,
                             const float* __restrict__ deg, const float* __restrict__ gcn_bias,
                             const int* __restrict__ lengths)
{
    size_t idx = (size_t)blockIdx.x * 256 + threadIdx.x;
    int j = (int)(idx >> 8);
    int d = (int)(idx & 255);
    float dg = deg[j];
    float a  = (agg1[idx] + aggM[idx] + (y1[idx] + sb[d]) / dg) / dg;
    float h  = tanhf(a + gcn_bias[d]);
    int b = j >> 9, p = j & 511;
    if (p >= lengths[b]) h = 0.f;
    aggM[idx] = h;
}

__global__ void bn_stats(const float* __restrict__ X, float* __restrict__ sums,
                         float* __restrict__ sumsq, int R)
{
    int t = threadIdx.x;
    float s = 0.f, q = 0.f;
    for (int r = blockIdx.x; r < R; r += gridDim.x) {
        float v = X[(size_t)r * DD + t];
        s += v; q += v * v;
    }
    atomicAdd(&sums[t], s);
    atomicAdd(&sumsq[t], q);
}

// X normalized in place; optional bf16 duplicate (GEMM A input)
__global__ void bn_apply(float* __restrict__ X, const float* __restrict__ sums,
                         const float* __restrict__ sumsq, const float* __restrict__ g,
                         const float* __restrict__ bt, int R, u16* __restrict__ dup)
{
    size_t idx = (size_t)blockIdx.x * 256 + threadIdx.x;
    int d = (int)(idx & 255);
    float invR = 1.f / (float)R;
    float m   = sums[d] * invR;
    float var = sumsq[d] * invR - m * m;
    float v = (X[idx] - m) * rsqrtf(fmaxf(var, 0.f) + EPSF) * g[d] + bt[d];
    X[idx] = v;
    if (dup) dup[idx] = f2bu(v);
}

// ---------------------------------------------------------------------------
// MFMA flash attention. One block per (b, h, 64-row q-tile); out bf16.
// ---------------------------------------------------------------------------
__global__ __launch_bounds__(256)
void attn_mfma(const bf16* __restrict__ qkv, u16* __restrict__ out)
{
    const int bid = blockIdx.x;
    const int qt = bid & 7;
    const int h  = (bid >> 3) & 3;
    const int b  = bid >> 5;

    const int tid  = threadIdx.x;
    const int lane = tid & 63;
    const int wv   = tid >> 6;
    const int fr   = lane & 15;
    const int quad = lane >> 4;
    const int q8   = quad * 8;

    __shared__ u16 Qs[64][72];
    __shared__ u16 Ks[128][72];
    __shared__ u16 Vts[64][136];
    __shared__ u16 Ps[64][136];

    const u16* qb = (const u16*)qkv;
    const size_t bb = (size_t)(b * NN);

#pragma unroll
    for (int i = 0; i < 2; i++) {
        int idx = i * 256 + tid;
        int r = idx >> 3, seg = idx & 7;
        uint4 u = *((const uint4*)(qb + (bb + qt * 64 + r) * 768 + h * 64) + seg);
        *(uint4*)&Qs[r][seg * 8] = u;
    }

    f32x4 O[4];
#pragma unroll
    for (int t = 0; t < 4; t++) O[t] = (f32x4){0.f, 0.f, 0.f, 0.f};
    float m_i[4] = {-1e30f, -1e30f, -1e30f, -1e30f};
    float l_i[4] = {0.f, 0.f, 0.f, 0.f};

    for (int c = 0; c < 4; c++) {
        __syncthreads();
#pragma unroll
        for (int i = 0; i < 4; i++) {
            int idx = i * 256 + tid;
            int r = idx >> 3, seg = idx & 7;
            uint4 u = *((const uint4*)(qb + (bb + c * 128 + r) * 768 + 256 + h * 64) + seg);
            *(uint4*)&Ks[r][seg * 8] = u;
            uint4 v = *((const uint4*)(qb + (bb + c * 128 + r) * 768 + 512 + h * 64) + seg);
            u16* dst = &Vts[seg * 8][r];
            dst[0*136] = (u16)(v.x & 0xffff); dst[1*136] = (u16)(v.x >> 16);
            dst[2*136] = (u16)(v.y & 0xffff); dst[3*136] = (u16)(v.y >> 16);
            dst[4*136] = (u16)(v.z & 0xffff); dst[5*136] = (u16)(v.z >> 16);
            dst[6*136] = (u16)(v.w & 0xffff); dst[7*136] = (u16)(v.w >> 16);
        }
        __syncthreads();

        f32x4 S[8];
#pragma unroll
        for (int t = 0; t < 8; t++) S[t] = (f32x4){0.f, 0.f, 0.f, 0.f};
#pragma unroll
        for (int ks = 0; ks < 2; ks++) {
            short8 aq = *(const short8*)&Qs[wv * 16 + fr][ks * 32 + q8];
#pragma unroll
            for (int t = 0; t < 8; t++) {
                short8 bk = *(const short8*)&Ks[t * 16 + fr][ks * 32 + q8];
                S[t] = __builtin_amdgcn_mfma_f32_16x16x32_bf16(aq, bk, S[t], 0, 0, 0);
            }
        }

        float mc[4];
#pragma unroll
        for (int r = 0; r < 4; r++) {
            float mm = -1e30f;
#pragma unroll
            for (int t = 0; t < 8; t++) { S[t][r] *= 0.125f; mm = fmaxf(mm, S[t][r]); }
            mc[r] = mm;
        }
#pragma unroll
        for (int msk = 1; msk < 16; msk <<= 1)
#pragma unroll
            for (int r = 0; r < 4; r++) mc[r] = fmaxf(mc[r], __shfl_xor(mc[r], msk));

        float alpha[4], ls[4];
#pragma unroll
        for (int r = 0; r < 4; r++) {
            float mn = fmaxf(m_i[r], mc[r]);
            alpha[r] = __expf(m_i[r] - mn);
            m_i[r] = mn;
            ls[r] = 0.f;
        }
#pragma unroll
        for (int t = 0; t < 8; t++)
#pragma unroll
            for (int r = 0; r < 4; r++) {
                float p = __expf(S[t][r] - m_i[r]);
                Ps[wv * 16 + quad * 4 + r][t * 16 + fr] = f2bu(p);
                ls[r] += p;
            }
#pragma unroll
        for (int msk = 1; msk < 16; msk <<= 1)
#pragma unroll
            for (int r = 0; r < 4; r++) ls[r] += __shfl_xor(ls[r], msk);
#pragma unroll
        for (int r = 0; r < 4; r++) l_i[r] = l_i[r] * alpha[r] + ls[r];
#pragma unroll
        for (int t = 0; t < 4; t++)
#pragma unroll
            for (int r = 0; r < 4; r++) O[t][r] *= alpha[r];

#pragma unroll
        for (int ks = 0; ks < 4; ks++) {
            short8 ap = *(const short8*)&Ps[wv * 16 + fr][ks * 32 + q8];
#pragma unroll
            for (int t = 0; t < 4; t++) {
                short8 bv = *(const short8*)&Vts[t * 16 + fr][ks * 32 + q8];
                O[t] = __builtin_amdgcn_mfma_f32_16x16x32_bf16(ap, bv, O[t], 0, 0, 0);
            }
        }
    }

#pragma unroll
    for (int t = 0; t < 4; t++)
#pragma unroll
        for (int r = 0; r < 4; r++) {
            int q = qt * 64 + wv * 16 + quad * 4 + r;
            out[(bb + q) * 256 + h * 64 + t * 16 + fr] = f2bu(O[t][r] / l_i[r]);
        }
}

// out = LN(X + Y); optional bf16 duplicate. One block per row of 256.
__global__ void add_ln_kernel(const float* __restrict__ X, const float* __restrict__ Y,
                              const float* __restrict__ g, const float* __restrict__ bt,
                              float* __restrict__ out, u16* __restrict__ dup)
{
    int row = blockIdx.x;
    int t   = threadIdx.x;
    size_t idx = (size_t)row * DD + t;
    float v = X[idx] + Y[idx];
    __shared__ float red[DD];
    red[t] = v; __syncthreads();
    for (int s = 128; s > 0; s >>= 1) { if (t < s) red[t] += red[t + s]; __syncthreads(); }
    float m = red[0] * (1.f / DD);
    __syncthreads();
    float d = v - m;
    red[t] = d * d; __syncthreads();
    for (int s = 128; s > 0; s >>= 1) { if (t < s) red[t] += red[t + s]; __syncthreads(); }
    float var = red[0] * (1.f / DD);
    float o = d * rsqrtf(var + EPSF) * g[t] + bt[t];
    out[idx] = o;
    if (dup) dup[idx] = f2bu(o);
}

__global__ void pool_kernel(const float* __restrict__ enc, const int* __restrict__ lengths,
                            float* __restrict__ poolbuf)
{
    int b = blockIdx.x;
    int t = threadIdx.x;
    int L = lengths[b];
    if (L < 1) L = 1;
    const float* p = enc + (size_t)b * NN * DD + t;
    float s = 0.f, mx = -1e30f;
    for (int n = 0; n < NN; n++) {
        float v = p[(size_t)n * DD];
        s += v;
        if (n < L) mx = fmaxf(mx, v);
    }
    poolbuf[b * 512 + t]       = mx;
    poolbuf[b * 512 + 256 + t] = s / (float)L;
}

__global__ void head_kernel(const float* __restrict__ poolbuf, const float* __restrict__ lin_w,
                            const float* __restrict__ lin_b, const float* __restrict__ g,
                            const float* __restrict__ bt, float* __restrict__ out)
{
    int b = threadIdx.x;
    float r0 = lin_b[0], r1 = lin_b[1];
    for (int k = 0; k < 512; k++) {
        float p = poolbuf[b * 512 + k];
        r0 += p * lin_w[k];
        r1 += p * lin_w[512 + k];
    }
    __shared__ float s0[64], s1[64], mstat[4];
    s0[b] = r0; s1[b] = r1; __syncthreads();
    if (b == 0) {
        float a0 = 0, a1 = 0, q0 = 0, q1 = 0;
        for (int i = 0; i < 64; i++) { a0 += s0[i]; a1 += s1[i]; }
        a0 *= (1.f / 64.f); a1 *= (1.f / 64.f);
        for (int i = 0; i < 64; i++) {
            float d0 = s0[i] - a0, d1 = s1[i] - a1;
            q0 += d0 * d0; q1 += d1 * d1;
        }
        mstat[0] = a0; mstat[1] = a1; mstat[2] = q0 * (1.f / 64.f); mstat[3] = q1 * (1.f / 64.f);
    }
    __syncthreads();
    float z0 = (r0 - mstat[0]) * rsqrtf(mstat[2] + EPSF) * g[0] + bt[0];
    float z1 = (r1 - mstat[1]) * rsqrtf(mstat[3] + EPSF) * g[1] + bt[1];
    float mx = fmaxf(z0, z1);
    float e0 = __expf(z0 - mx), e1 = __expf(z1 - mx);
    float inv = 1.f / (e0 + e1);
    out[b * 2 + 0] = e0 * inv;
    out[b * 2 + 1] = e1 * inv;
}

extern "C" void kernel_launch(void* const* d_in, const int* in_sizes, int n_in,
                              void* d_out, int out_size, void* d_ws, size_t ws_size,
                              hipStream_t stream)
{
    (void)in_sizes; (void)n_in; (void)out_size; (void)ws_size;
    const float* x          = (const float*)d_in[0];
    const float* edge_attr  = (const float*)d_in[1];
    const float* W1         = (const float*)d_in[5];
    const float* W2         = (const float*)d_in[6];
    const float* W3         = (const float*)d_in[7];
    const float* b3         = (const float*)d_in[8];
    const float* gcn_bias   = (const float*)d_in[9];
    const float* bn1_g      = (const float*)d_in[10];
    const float* bn1_b      = (const float*)d_in[11];
    const float* in_proj_w  = (const float*)d_in[12];
    const float* in_proj_b  = (const float*)d_in[13];
    const float* out_proj_w = (const float*)d_in[14];
    const float* out_proj_b = (const float*)d_in[15];
    const float* ln1_g      = (const float*)d_in[16];
    const float* ln1_b      = (const float*)d_in[17];
    const float* lin1_w     = (const float*)d_in[18];
    const float* lin1_b     = (const float*)d_in[19];
    const float* lin2_w     = (const float*)d_in[20];
    const float* lin2_b     = (const float*)d_in[21];
    const float* ln2_g      = (const float*)d_in[22];
    const float* ln2_b      = (const float*)d_in[23];
    const float* bn2_g      = (const float*)d_in[24];
    const float* bn2_b      = (const float*)d_in[25];
    const float* lin_w      = (const float*)d_in[26];
    const float* lin_b      = (const float*)d_in[27];
    const float* bn3_g      = (const float*)d_in[28];
    const float* bn3_b      = (const float*)d_in[29];

    // ---- Workspace layout (~185 MB) ----
    char* p = (char*)d_ws;
    u16*   big   = (u16*)p;   p += (size_t)BN_TOT * 1024 * 2;   // 64 MiB: [xb|xsb|eaggb] -> qkv -> ffa
    float* bufA  = (float*)p; p += (size_t)BN_TOT * 256 * 4;    // aggM/h -> ffb
    float* bufB  = (float*)p; p += (size_t)BN_TOT * 256 * 4;    // y1 -> attnp -> h2
    float* bufC  = (float*)p; p += (size_t)BN_TOT * 256 * 4;    // agg1 -> h1
    u16*   bufP  = (u16*)p;   p += (size_t)BN_TOT * 256 * 2;    // 16.8 MB: hb -> attnoutb -> h1b
    float* deg   = (float*)p; p += (size_t)BN_TOT * 4;
    u16*   Mb    = (u16*)p;   p += 256 * 64 * 2;
    float* sb    = (float*)p; p += 1024;
    float* stats = (float*)p; p += 4 * 256 * 4;
    float* poolbuf=(float*)p; p += 64 * 512 * 4;
    int*   flags = (int*)p;   p += 256;
    int*   erc   = (int*)p;   p += BE_TOT * 4;
    int*   ecc   = (int*)p;   p += BE_TOT * 4;
    int*   lenc  = (int*)p;   p += 256;
    int*   sorted= (int*)p;   p += BE_TOT * 4;
    int*   noff  = (int*)p;   p += BN_TOT * 4;
    u16*   W1b   = (u16*)p;   p += 256 * 320 * 2;
    u16*   W3ab  = (u16*)p;   p += 256 * 256 * 2;
    u16*   ipwb  = (u16*)p;   p += 768 * 256 * 2;
    u16*   opwb  = (u16*)p;   p += 256 * 256 * 2;
    u16*   l1wb  = (u16*)p;   p += 1024 * 256 * 2;
    u16*   l2wb  = (u16*)p;   p += 256 * 1024 * 2;

    // bf16 temporaries inside big (all dead before qkv is written at in_proj)
    u16* xb    = big;                              // 32768 x 320
    u16* xsb   = big + (size_t)BN_TOT * 320;       // 32768 x 256
    u16* eaggb = big + (size_t)BN_TOT * (320+256); // 32768 x 64
    bf16* qkv  = (bf16*)big;
    bf16* ffa  = (bf16*)big;

    float* y1      = bufB;
    float* agg1    = bufC;
    float* aggM    = bufA;    // becomes h in finalize
    float* h       = bufA;
    u16*   hb      = bufP;
    u16*   attnoutb= bufP;    // hb dead after in_proj GEMM
    float* attnp   = bufB;    // y1 dead after finalize
    float* h1      = bufC;    // agg1 dead after finalize
    u16*   h1b     = bufP;    // attnoutb dead after out_proj GEMM
    float* ffb     = bufA;    // h dead after add_ln #1
    float* h2      = bufB;    // attnp dead after add_ln #1

    hipMemsetAsync(stats, 0, 4 * 256 * 4, stream);

    detect_kernel<<<1, 1, 0, stream>>>((const int*)d_in[4], flags);
    conv_i<<<(BE_TOT + 255) / 256, 256, 0, stream>>>(d_in[2], erc, BE_TOT, flags);
    conv_i<<<(BE_TOT + 255) / 256, 256, 0, stream>>>(d_in[3], ecc, BE_TOT, flags);
    conv_i<<<1, 64, 0, stream>>>(d_in[4], lenc, BB, flags);

    // weight / input bf16 conversions (one pass, ~45 MB total traffic)
    conv_pad<<<(BN_TOT * 320 + 255) / 256, 256, 0, stream>>>(x, xb, BN_TOT, FINK, 320);
    conv_pad<<<(256 * 320 + 255) / 256, 256, 0, stream>>>(W1, W1b, 256, FINK, 320);
    conv_w3a<<<256, 256, 0, stream>>>(W3, W3ab);
    conv_f2b<<<(768 * 256 + 255) / 256, 256, 0, stream>>>(in_proj_w, ipwb, 768 * 256);
    conv_f2b<<<(256 * 256 + 255) / 256, 256, 0, stream>>>(out_proj_w, opwb, 256 * 256);
    conv_f2b<<<(1024 * 256 + 255) / 256, 256, 0, stream>>>(lin1_w, l1wb, 1024 * 256);
    conv_f2b<<<(256 * 1024 + 255) / 256, 256, 0, stream>>>(lin2_w, l2wb, 256 * 1024);

    prep_M<<<256, 64, 0, stream>>>(W3, W2, Mb, sb);
    sort_edges<<<BB, 512, 0, stream>>>(ecc, deg, noff, sorted);

    // xs = x @ W1.T  (bf16 out, K padded to 320)
    gemm_bf<bf16, 0><<<dim3(2, 256), 256, 0, stream>>>(
        xb, W1b, nullptr, (bf16*)xsb, BN_TOT, 256, 320, 320, 320);
    // y1 = xs @ W3a.T + b3
    gemm_bf<float, 0><<<dim3(2, 256), 256, 0, stream>>>(
        xsb, W3ab, b3, y1, BN_TOT, 256, 256, 256, 256);

    edge_gather<<<BN_TOT, 256, 0, stream>>>(erc, sorted, noff, deg, y1, edge_attr, agg1, eaggb);
    gemm_bf<float, 0><<<dim3(2, 256), 256, 0, stream>>>(
        eaggb, Mb, nullptr, aggM, BN_TOT, 256, 64, 64, 64);

    gcn_finalize<<<BN_TOT, 256, 0, stream>>>(agg1, aggM, y1, sb, deg, gcn_bias, lenc);

    bn_stats<<<512, 256, 0, stream>>>(h, stats, stats + 256, BN_TOT);
    bn_apply<<<BN_TOT, 256, 0, stream>>>(h, stats, stats + 256, bn1_g, bn1_b, BN_TOT, hb);

    gemm_bf<bf16, 0><<<dim3(6, 256), 256, 0, stream>>>(
        hb, ipwb, in_proj_b, qkv, BN_TOT, 768, 256, 256, 256);

    attn_mfma<<<BB * 4 * 8, 256, 0, stream>>>(qkv, attnoutb);

    gemm_bf<float, 0><<<dim3(2, 256), 256, 0, stream>>>(
        attnoutb, opwb, out_proj_b, attnp, BN_TOT, 256, 256, 256, 256);

    add_ln_kernel<<<BN_TOT, 256, 0, stream>>>(h, attnp, ln1_g, ln1_b, h1, h1b);

    gemm_bf<bf16, 1><<<dim3(8, 256), 256, 0, stream>>>(
        h1b, l1wb, lin1_b, ffa, BN_TOT, 1024, 256, 256, 256);
    gemm_bf<float, 0><<<dim3(2, 256), 256, 0, stream>>>(
        (const u16*)ffa, l2wb, lin2_b, ffb, BN_TOT, 256, 1024, 1024, 1024);

    add_ln_kernel<<<BN_TOT, 256, 0, stream>>>(h1, ffb, ln2_g, ln2_b, h2, nullptr);

    bn_stats<<<512, 256, 0, stream>>>(h2, stats + 512, stats + 768, BN_TOT);
    bn_apply<<<BN_TOT, 256, 0, stream>>>(h2, stats + 512, stats + 768, bn2_g, bn2_b, BN_TOT, nullptr);

    pool_kernel<<<64, 256, 0, stream>>>(h2, lenc, poolbuf);
    head_kernel<<<1, 64, 0, stream>>>(poolbuf, lin_w, lin_b, bn3_g, bn3_b, (float*)d_out);
}